// Round 9
// baseline (446.308 us; speedup 1.0000x reference)
//
#include <hip/hip_runtime.h>
#include <math.h>

#define N_ATOMS 4096
#define N_EDGES 131072
#define PI6 0.52359877559829887f

typedef __attribute__((ext_vector_type(8))) short bf16x8;
typedef __attribute__((ext_vector_type(4))) float f32x4;

__device__ __forceinline__ float silu_f(float x){ return x / (1.f + __expf(-x)); }
__device__ __forceinline__ float sigmoid_f(float x){ return 1.f / (1.f + __expf(-x)); }
__device__ __forceinline__ float bcastf(float v, int k){
  return __int_as_float(__builtin_amdgcn_readlane(__float_as_int(v), k));
}
__device__ __forceinline__ unsigned int f2bf(float f){
  unsigned int u = __float_as_uint(f);
  return (u + 0x7FFFu + ((u>>16)&1u)) >> 16;
}
__device__ __forceinline__ bf16x8 ld8(const unsigned short* p){
  union { unsigned int u[4]; bf16x8 v; } r;
  const unsigned int* q = (const unsigned int*)p;
  r.u[0]=q[0]; r.u[1]=q[1]; r.u[2]=q[2]; r.u[3]=q[3];
  return r.v;
}

// ---------- transpose attn_w_in (384x128) and attn_w_out (128x128) ----------
__global__ __launch_bounds__(256) void transpose_kernel(
  const float* __restrict__ win, const float* __restrict__ wout,
  float* __restrict__ wt_in, float* __restrict__ wt_out){
  int idx = blockIdx.x*256 + threadIdx.x;
  if (idx < 384*128){ int i = idx>>7, k = idx&127; wt_in[k*384+i] = win[idx]; }
  else { int j = idx - 384*128; int i = j>>7, k = j&127; wt_out[k*128+i] = wout[j]; }
}

// ---------- counting sort of edges by destination ----------
__global__ void hist_kernel(const int* __restrict__ edge_index, int* __restrict__ counts){
  int e = blockIdx.x*blockDim.x + threadIdx.x;
  if (e < N_EDGES) atomicAdd(&counts[edge_index[N_EDGES + e]], 1);
}

__global__ void scan_kernel(const int* __restrict__ counts, int* __restrict__ offsets){
  __shared__ int buf[4096];
  int t = threadIdx.x; // 1024 threads
  for (int i=t;i<4096;i+=1024) buf[i]=counts[i];
  __syncthreads();
  for (int off=1; off<4096; off<<=1){
    int v[4];
    #pragma unroll
    for (int k=0;k<4;k++){ int i=t+k*1024; v[k] = (i>=off)?buf[i-off]:0; }
    __syncthreads();
    #pragma unroll
    for (int k=0;k<4;k++){ int i=t+k*1024; buf[i]+=v[k]; }
    __syncthreads();
  }
  for (int i=t;i<4096;i+=1024) offsets[i]=buf[i]-counts[i]; // exclusive
  if (t==0) offsets[4096]=buf[4095];
}

__global__ void scatter_kernel(const int* __restrict__ edge_index, const int* __restrict__ offsets,
                               int* __restrict__ cursor, int* __restrict__ edge_list){
  int e = blockIdx.x*blockDim.x + threadIdx.x;
  if (e < N_EDGES){
    int d = edge_index[N_EDGES + e];
    int pos = atomicAdd(&cursor[d], 1);
    edge_list[offsets[d] + pos] = e;
  }
}

// ---------- per-atom edge features -> F (planar [9][N_ATOMS*128]) ----------
// 512 thr = 4 edge-groups x 128 channels; 4-edge batches so each rad_w2 L1
// load feeds 4 FMAs (compiler refuses to keep w2 column resident: R8).
__global__ __launch_bounds__(512) void edge_F_kernel(
  const float* __restrict__ edge_vectors, const float* __restrict__ edge_lengths,
  const float* __restrict__ rad_w1, const float* __restrict__ rad_b1,
  const float* __restrict__ rad_w2, const float* __restrict__ rad_b2,
  const int* __restrict__ offsets, const int* __restrict__ edge_list,
  float* __restrict__ Fp)
{
  const int a = blockIdx.x, tid = threadIdx.x;
  const int g = tid >> 7;        // edge group 0..3
  const int t = tid & 127;       // channel
  const int lane = tid & 63;
  __shared__ float Fred[4][128][9];   // 18 KB

  float w1r[8];
  #pragma unroll
  for (int k=0;k<8;k++)  w1r[k] = rad_w1[k*64 + lane];
  const float b1l = rad_b1[lane], b2c = rad_b2[t];
  float F9[9];
  #pragma unroll
  for (int j=0;j<9;j++) F9[j]=0.f;

  const int beg = offsets[a], end = offsets[a+1];
  for (int ei = beg + g*4; ei < end; ei += 16){
    float xs[4], ys[4], zs[4], vf[4], rb[4], r1[4];
    #pragma unroll
    for (int s=0;s<4;s++){
      int idx = ei + s;
      vf[s] = (idx < end) ? 1.f : 0.f;
      int e = __builtin_amdgcn_readfirstlane(edge_list[(idx < end) ? idx : beg]);
      float vx = edge_vectors[e*3], vy = edge_vectors[e*3+1], vz = edge_vectors[e*3+2];
      float d  = edge_lengths[e];
      float rn = sqrtf(vx*vx+vy*vy+vz*vz) + 1e-8f;
      xs[s] = vx/rn; ys[s] = vy/rn; zs[s] = vz/rn;
      float rbv = 0.f;
      if (lane < 8){
        float cut = 0.5f*(__cosf(d*PI6)+1.f)*(d<6.f?1.f:0.f);
        rbv = __sinf(d*((float)(lane+1)*PI6))/d*cut;
      }
      rb[s] = rbv;
    }
    #pragma unroll
    for (int s=0;s<4;s++){
      float pa = b1l, pb = 0.f;
      #pragma unroll
      for (int k=0;k<8;k+=2){
        pa += bcastf(rb[s],k  )*w1r[k  ];
        pb += bcastf(rb[s],k+1)*w1r[k+1];
      }
      r1[s] = silu_f(pa+pb);
    }
    float r2[4] = {b2c, b2c, b2c, b2c};
    #pragma unroll
    for (int k=0;k<64;k++){
      float w = rad_w2[k*128 + t];
      r2[0] += bcastf(r1[0],k)*w;
      r2[1] += bcastf(r1[1],k)*w;
      r2[2] += bcastf(r1[2],k)*w;
      r2[3] += bcastf(r1[3],k)*w;
    }
    #pragma unroll
    for (int s=0;s<4;s++){
      float r2v = silu_f(r2[s]) * vf[s];
      float x = xs[s], y = ys[s], z = zs[s];
      F9[0] += r2v;
      F9[1] += r2v*y;
      F9[2] += r2v*z;
      F9[3] += r2v*x;
      F9[4] += r2v*(3.f*z*z - 1.f);
      F9[5] += r2v*(x*z);
      F9[6] += r2v*(y*z);
      F9[7] += r2v*(x*y);
      F9[8] += r2v*(x*x - y*y);
    }
  }

  #pragma unroll
  for (int j=0;j<9;j++) Fred[g][t][j] = F9[j];
  __syncthreads();
  if (g==0){
    #pragma unroll
    for (int j=0;j<9;j++)
      Fp[j*(N_ATOMS*128) + a*128 + t] = F9[j] + Fred[1][t][j] + Fred[2][t][j] + Fred[3][t][j];
  }
}

// ---------- node update: agg -> msg MLP -> qkv ; 8 atoms, 512 threads ----------
__global__ __launch_bounds__(512) void node_kernel(
  const int* __restrict__ atomic_numbers, const float* __restrict__ atom_embed,
  const float* __restrict__ tp_w, const float* __restrict__ tp_b,
  const float* __restrict__ msg_w1, const float* __restrict__ msg_b1,
  const float* __restrict__ msg_w2, const float* __restrict__ msg_b2,
  const float* __restrict__ wt_in, const float* __restrict__ attn_b_in,
  const int* __restrict__ offsets, const float* __restrict__ Fp,
  float* __restrict__ upd_out, float* __restrict__ qkv_out)
{
  const int a0 = blockIdx.x*8, tid = threadIdx.x;
  const int g = tid >> 7, o = tid & 127;
  __shared__ float red[4][8][128];   // 16 KB
  __shared__ float combs[8][192];
  __shared__ float hids[8][128];
  __shared__ float upds[8][128];

  float acc[8];
  #pragma unroll
  for (int a8=0;a8<8;a8++) acc[a8] = 0.f;

  const float4* Fp4 = (const float4*)Fp;
  for (int c4=g*8; c4<g*8+8; c4++){
    #pragma unroll
    for (int j=0;j<9;j++){
      float4 f[8];
      #pragma unroll
      for (int a8=0;a8<8;a8++) f[a8] = Fp4[j*(N_ATOMS*32) + (a0+a8)*32 + c4];
      #pragma unroll
      for (int cc=0;cc<4;cc++){
        int c = c4*4+cc;
        int row = (j==0)? c : (j<4 ? 128 + c*3 + (j-1) : 512 + c*5 + (j-4));
        float w = tp_w[row*128+o];
        #pragma unroll
        for (int a8=0;a8<8;a8++){
          float fv = (cc==0)?f[a8].x:(cc==1)?f[a8].y:(cc==2)?f[a8].z:f[a8].w;
          acc[a8] += fv*w;
        }
      }
    }
  }
  #pragma unroll
  for (int a8=0;a8<8;a8++) red[g][a8][o] = acc[a8];
  { int a8 = tid>>6, k = tid&63;
    combs[a8][k] = atom_embed[atomic_numbers[a0+a8]*64 + k]; }
  __syncthreads();
  if (g==0){
    const float tb = tp_b[o];
    #pragma unroll
    for (int a8=0;a8<8;a8++){
      float deg = (float)(offsets[a0+a8+1]-offsets[a0+a8]);
      combs[a8][64+o] = red[0][a8][o]+red[1][a8][o]+red[2][a8][o]+red[3][a8][o] + tb*deg;
    }
  }
  __syncthreads();

  const int aA = 2*g, aB = 2*g+1;
  {
    float hA = msg_b1[o], hB = hA;
    for (int k=0;k<192;k++){
      float w = msg_w1[k*128+o];
      hA += combs[aA][k]*w; hB += combs[aB][k]*w;
    }
    hids[aA][o] = silu_f(hA); hids[aB][o] = silu_f(hB);
  }
  __syncthreads();
  {
    float uA = msg_b2[o], uB = uA;
    for (int k=0;k<128;k++){
      float w = msg_w2[k*128+o];
      uA += hids[aA][k]*w; uB += hids[aB][k]*w;
    }
    upds[aA][o]=uA; upds[aB][o]=uB;
    upd_out[(a0+aA)*128+o]=uA; upd_out[(a0+aB)*128+o]=uB;
  }
  __syncthreads();
  for (int p=0;p<3;p++){
    float qA = attn_b_in[p*128+o], qB = qA;
    for (int k=0;k<128;k++){
      float w = wt_in[k*384 + p*128 + o];
      qA += upds[aA][k]*w; qB += upds[aB][k]*w;
    }
    qkv_out[(a0+aA)*384 + p*128 + o] = qA;
    qkv_out[(a0+aB)*384 + p*128 + o] = qB;
  }
}

// ---------- MFMA flash attention: 4 heads, N=4096, D=32, bf16 matmuls ----------
// block: 32 queries x 1 head, 256 thr = 8 waves = (2 q-groups) x (2 key-halves)
__global__ __launch_bounds__(256) void attn_kernel(const float* __restrict__ qkv, float* __restrict__ att){
  const int b = blockIdx.x;
  const int h = b >> 7, qt = b & 127;      // 4 heads, 128 q-tiles of 32
  const int tid = threadIdx.x;
  const int w = tid >> 6, lane = tid & 63;
  const int wq = w & 1, wk = w >> 1;       // query group, key half
  const int l15 = lane & 15, lg = lane >> 4;
  const int n0 = qt*32;

  __shared__ unsigned short Qs[32][36];
  __shared__ unsigned short Ks[2][2][64][36];
  __shared__ unsigned short Vt[2][2][32][66];
  __shared__ unsigned short Ps[8][16][68];
  __shared__ float MB[2][64][16];

  const float scale = 0.17677669529663687f; // 1/sqrt(32)

  // ---- stage Q (scaled) ----
  {
    int qr = tid>>3, d4 = (tid&7)*4;
    const float4 qf = *(const float4*)(qkv + (size_t)(n0+qr)*384 + h*32 + d4);
    unsigned int* dst = (unsigned int*)&Qs[qr][d4];
    dst[0] = f2bf(qf.x*scale) | (f2bf(qf.y*scale)<<16);
    dst[1] = f2bf(qf.z*scale) | (f2bf(qf.w*scale)<<16);
  }

  // staging thread mapping: half hf = tid>>7 stages tile (hf*32 + t)
  const int hf = tid >> 7, u = tid & 127;
  const int skey = u >> 1, sd16 = (u & 1)*16;
  float4 kA,kB,kC,kD, vA,vB,vC,vD;

  #define LOADG(T) { \
    const float* kp = qkv + (size_t)(((hf*32+(T))*64 + skey))*384 + 128 + h*32 + sd16; \
    kA = *(const float4*)kp;        kB = *(const float4*)(kp+4); \
    kC = *(const float4*)(kp+8);    kD = *(const float4*)(kp+12); \
    const float* vp = kp + 128; \
    vA = *(const float4*)vp;        vB = *(const float4*)(vp+4); \
    vC = *(const float4*)(vp+8);    vD = *(const float4*)(vp+12); }

  #define WRITEL(BUF) { \
    unsigned int* kdst = (unsigned int*)&Ks[BUF][hf][skey][sd16]; \
    kdst[0]=f2bf(kA.x)|(f2bf(kA.y)<<16); kdst[1]=f2bf(kA.z)|(f2bf(kA.w)<<16); \
    kdst[2]=f2bf(kB.x)|(f2bf(kB.y)<<16); kdst[3]=f2bf(kB.z)|(f2bf(kB.w)<<16); \
    kdst[4]=f2bf(kC.x)|(f2bf(kC.y)<<16); kdst[5]=f2bf(kC.z)|(f2bf(kC.w)<<16); \
    kdst[6]=f2bf(kD.x)|(f2bf(kD.y)<<16); kdst[7]=f2bf(kD.z)|(f2bf(kD.w)<<16); \
    Vt[BUF][hf][sd16+ 0][skey]=(unsigned short)f2bf(vA.x); \
    Vt[BUF][hf][sd16+ 1][skey]=(unsigned short)f2bf(vA.y); \
    Vt[BUF][hf][sd16+ 2][skey]=(unsigned short)f2bf(vA.z); \
    Vt[BUF][hf][sd16+ 3][skey]=(unsigned short)f2bf(vA.w); \
    Vt[BUF][hf][sd16+ 4][skey]=(unsigned short)f2bf(vB.x); \
    Vt[BUF][hf][sd16+ 5][skey]=(unsigned short)f2bf(vB.y); \
    Vt[BUF][hf][sd16+ 6][skey]=(unsigned short)f2bf(vB.z); \
    Vt[BUF][hf][sd16+ 7][skey]=(unsigned short)f2bf(vB.w); \
    Vt[BUF][hf][sd16+ 8][skey]=(unsigned short)f2bf(vC.x); \
    Vt[BUF][hf][sd16+ 9][skey]=(unsigned short)f2bf(vC.y); \
    Vt[BUF][hf][sd16+10][skey]=(unsigned short)f2bf(vC.z); \
    Vt[BUF][hf][sd16+11][skey]=(unsigned short)f2bf(vC.w); \
    Vt[BUF][hf][sd16+12][skey]=(unsigned short)f2bf(vD.x); \
    Vt[BUF][hf][sd16+13][skey]=(unsigned short)f2bf(vD.y); \
    Vt[BUF][hf][sd16+14][skey]=(unsigned short)f2bf(vD.z); \
    Vt[BUF][hf][sd16+15][skey]=(unsigned short)f2bf(vD.w); }

  LOADG(0);
  WRITEL(0);
  __syncthreads();

  // A-fragment for Q (after barrier so Qs is complete)
  bf16x8 aQ = ld8(&Qs[wq*16 + l15][lg*8]);

  float m[4] = {-3e38f,-3e38f,-3e38f,-3e38f};
  float su[4] = {0.f,0.f,0.f,0.f};
  f32x4 oacc[2] = {{0.f,0.f,0.f,0.f},{0.f,0.f,0.f,0.f}};

  for (int t=0; t<32; t++){
    const int cur = t&1;
    if (t<31) LOADG(t+1);

    // QK^T: 4 MFMA, S tile 16q x 64k
    f32x4 s[4];
    #pragma unroll
    for (int n=0;n<4;n++){
      bf16x8 bK = ld8(&Ks[cur][wk][n*16+l15][lg*8]);
      f32x4 z = {0.f,0.f,0.f,0.f};
      s[n] = __builtin_amdgcn_mfma_f32_16x16x32_bf16(aQ, bK, z, 0,0,0);
    }

    // online softmax
    float csc[4], psum[4];
    #pragma unroll
    for (int r=0;r<4;r++){
      float mloc = fmaxf(fmaxf(s[0][r], s[1][r]), fmaxf(s[2][r], s[3][r]));
      #pragma unroll
      for (int off=1; off<16; off<<=1) mloc = fmaxf(mloc, __shfl_xor(mloc, off, 64));
      float mn = fmaxf(m[r], mloc);
      csc[r] = __expf(m[r] - mn);
      m[r] = mn;
      psum[r] = 0.f;
    }
    #pragma unroll
    for (int n=0;n<4;n++){
      #pragma unroll
      for (int r=0;r<4;r++){
        float p = __expf(s[n][r] - m[r]);
        psum[r] += p;
        Ps[w][lg*4+r][n*16+l15] = (unsigned short)f2bf(p);
      }
    }
    #pragma unroll
    for (int r=0;r<4;r++){
      #pragma unroll
      for (int off=1; off<16; off<<=1) psum[r] += __shfl_xor(psum[r], off, 64);
      su[r] = su[r]*csc[r] + psum[r];
    }
    #pragma unroll
    for (int nd=0;nd<2;nd++){
      #pragma unroll
      for (int r=0;r<4;r++) oacc[nd][r] *= csc[r];
    }

    // PV: O(16q x 32d) += P(16x64) * V(64x32)
    #pragma unroll
    for (int c=0;c<2;c++){
      bf16x8 aP = ld8(&Ps[w][l15][c*32 + lg*8]);
      #pragma unroll
      for (int nd=0;nd<2;nd++){
        bf16x8 bV = ld8(&Vt[cur][wk][nd*16+l15][c*32 + lg*8]);
        oacc[nd] = __builtin_amdgcn_mfma_f32_16x16x32_bf16(aP, bV, oacc[nd], 0,0,0);
      }
    }

    __syncthreads();
    if (t<31) WRITEL((t+1)&1);
    __syncthreads();
  }

  // merge key-halves: wk=1 publishes, wk=0 merges and writes out
  if (wk==1){
    #pragma unroll
    for (int r=0;r<4;r++){ MB[wq][lane][r] = m[r]; MB[wq][lane][4+r] = su[r]; }
    #pragma unroll
    for (int nd=0;nd<2;nd++)
      #pragma unroll
      for (int r=0;r<4;r++) MB[wq][lane][8+nd*4+r] = oacc[nd][r];
  }
  __syncthreads();
  if (wk==0){
    #pragma unroll
    for (int r=0;r<4;r++){
      float m1 = MB[wq][lane][r], s1 = MB[wq][lane][4+r];
      float mf = fmaxf(m[r], m1);
      float c0 = __expf(m[r]-mf), c1 = __expf(m1-mf);
      float stot = su[r]*c0 + s1*c1;
      float inv = 1.f/stot;
      #pragma unroll
      for (int nd=0;nd<2;nd++){
        float o = oacc[nd][r]*c0 + MB[wq][lane][8+nd*4+r]*c1;
        att[(size_t)(n0 + wq*16 + lg*4 + r)*128 + h*32 + nd*16 + l15] = o*inv;
      }
    }
  }
  #undef LOADG
  #undef WRITEL
}

// ---------- epilogue: 8 atoms, 512 threads, LDS-staged operands ----------
__global__ __launch_bounds__(512) void final_kernel(
  const float* __restrict__ att, const float* __restrict__ upd,
  const float* __restrict__ wt_out, const float* __restrict__ attn_b_out,
  const float* __restrict__ gate_w, const float* __restrict__ gate_b,
  const float* __restrict__ out_w, const float* __restrict__ out_b,
  float* __restrict__ out)
{
  const int a0 = blockIdx.x*8, tid = threadIdx.x;
  const int g = tid >> 7, o = tid & 127;
  __shared__ float att_s[8][128], upd_s[8][128], tmps[8][128];
  for (int i=tid; i<1024; i+=512){
    int a8 = i>>7, k = i&127;
    att_s[a8][k] = att[(a0+a8)*128+k];
    upd_s[a8][k] = upd[(a0+a8)*128+k];
  }
  __syncthreads();
  const int aA = 2*g, aB = 2*g+1;
  float a2A = attn_b_out[o], a2B = a2A;
  float gA = gate_b[o], gB = gA;
  for (int k=0;k<128;k++){
    float wa = wt_out[k*128+o];
    float wg = gate_w[k*128+o];
    a2A += att_s[aA][k]*wa; a2B += att_s[aB][k]*wa;
    gA  += upd_s[aA][k]*wg; gB  += upd_s[aB][k]*wg;
  }
  gA = sigmoid_f(gA); gB = sigmoid_f(gB);
  tmps[aA][o] = gA*a2A + (1.f-gA)*upd_s[aA][o];
  tmps[aB][o] = gB*a2B + (1.f-gB)*upd_s[aB][o];
  __syncthreads();
  float ouA = out_b[o], ouB = ouA;
  for (int k=0;k<128;k++){
    float w = out_w[k*128+o];
    ouA += tmps[aA][k]*w; ouB += tmps[aB][k]*w;
  }
  out[(a0+aA)*128+o] = ouA;
  out[(a0+aB)*128+o] = ouB;
}

extern "C" void kernel_launch(void* const* d_in, const int* in_sizes, int n_in,
                              void* d_out, int out_size, void* d_ws, size_t ws_size,
                              hipStream_t stream){
  const int*   atomic_numbers = (const int*)  d_in[0];
  const int*   edge_index     = (const int*)  d_in[2];
  const float* edge_vectors   = (const float*)d_in[3];
  const float* edge_lengths   = (const float*)d_in[4];
  const float* atom_embed     = (const float*)d_in[5];
  const float* rad_w1 = (const float*)d_in[6];
  const float* rad_b1 = (const float*)d_in[7];
  const float* rad_w2 = (const float*)d_in[8];
  const float* rad_b2 = (const float*)d_in[9];
  const float* tp_w   = (const float*)d_in[10];
  const float* tp_b   = (const float*)d_in[11];
  const float* msg_w1 = (const float*)d_in[12];
  const float* msg_b1 = (const float*)d_in[13];
  const float* msg_w2 = (const float*)d_in[14];
  const float* msg_b2 = (const float*)d_in[15];
  const float* attn_w_in  = (const float*)d_in[16];
  const float* attn_b_in  = (const float*)d_in[17];
  const float* attn_w_out = (const float*)d_in[18];
  const float* attn_b_out = (const float*)d_in[19];
  const float* gate_w = (const float*)d_in[20];
  const float* gate_b = (const float*)d_in[21];
  const float* out_w  = (const float*)d_in[22];
  const float* out_b  = (const float*)d_in[23];

  // workspace layout (bytes)
  char* ws = (char*)d_ws;
  int* counts    = (int*)(ws);             // [0, 16384)
  int* cursor    = (int*)(ws + 16384);     // [16384, 32768)
  int* offsets   = (int*)(ws + 32768);     // [32768, 49156)  4097 ints
  int* edge_list = (int*)(ws + 53248);     // [53248, 577536)
  float* wt_in   = (float*)(ws + 577536);  // 128x384
  float* wt_out  = (float*)(ws + 774144);  // 128x128
  float* Fp      = (float*)(ws + 839680);  // [9][4096*128] = 18.9 MB
  float* att     = (float*)(ws + 839680);  // aliases Fp (dead before attn)
  float* upd     = (float*)(ws + 19714048);// 2 MB
  float* qkv     = (float*)(ws + 21811200);// 6.3 MB  (end 28102656)

  transpose_kernel<<<256, 256, 0, stream>>>(attn_w_in, attn_w_out, wt_in, wt_out);
  hipMemsetAsync(ws, 0, 32768, stream);  // counts + cursor
  hist_kernel<<<(N_EDGES+255)/256, 256, 0, stream>>>(edge_index, counts);
  scan_kernel<<<1, 1024, 0, stream>>>(counts, offsets);
  scatter_kernel<<<(N_EDGES+255)/256, 256, 0, stream>>>(edge_index, offsets, cursor, edge_list);
  edge_F_kernel<<<N_ATOMS, 512, 0, stream>>>(edge_vectors, edge_lengths,
      rad_w1, rad_b1, rad_w2, rad_b2, offsets, edge_list, Fp);
  node_kernel<<<N_ATOMS/8, 512, 0, stream>>>(atomic_numbers, atom_embed,
      tp_w, tp_b, msg_w1, msg_b1, msg_w2, msg_b2, wt_in, attn_b_in,
      offsets, Fp, upd, qkv);
  attn_kernel<<<512, 256, 0, stream>>>(qkv, att);
  final_kernel<<<N_ATOMS/8, 512, 0, stream>>>(att, upd, wt_out, attn_b_out,
      gate_w, gate_b, out_w, out_b, (float*)d_out);
}

// Round 10
// 338.733 us; speedup vs baseline: 1.3176x; 1.3176x over previous
//
#include <hip/hip_runtime.h>
#include <math.h>

#define N_ATOMS 4096
#define N_EDGES 131072
#define PI6 0.52359877559829887f

typedef __attribute__((ext_vector_type(8))) short bf16x8;
typedef __attribute__((ext_vector_type(4))) float f32x4;

__device__ __forceinline__ float silu_f(float x){ return x / (1.f + __expf(-x)); }
__device__ __forceinline__ float sigmoid_f(float x){ return 1.f / (1.f + __expf(-x)); }
__device__ __forceinline__ float bcastf(float v, int k){
  return __int_as_float(__builtin_amdgcn_readlane(__float_as_int(v), k));
}
__device__ __forceinline__ unsigned int f2bf(float f){
  unsigned int u = __float_as_uint(f);
  return (u + 0x7FFFu + ((u>>16)&1u)) >> 16;
}
__device__ __forceinline__ bf16x8 ld8(const unsigned short* p){
  union { unsigned int u[4]; bf16x8 v; } r;
  const unsigned int* q = (const unsigned int*)p;
  r.u[0]=q[0]; r.u[1]=q[1]; r.u[2]=q[2]; r.u[3]=q[3];
  return r.v;
}

// ---------- transposes + W2^T bf16 hi/lo planes ----------
__global__ __launch_bounds__(256) void transpose_kernel(
  const float* __restrict__ win, const float* __restrict__ wout,
  const float* __restrict__ rad_w2,
  float* __restrict__ wt_in, float* __restrict__ wt_out,
  unsigned short* __restrict__ w2t_h, unsigned short* __restrict__ w2t_l){
  int idx = blockIdx.x*256 + threadIdx.x;
  if (idx < 384*128){ int i = idx>>7, k = idx&127; wt_in[k*384+i] = win[idx]; }
  else if (idx < 384*128 + 128*128){
    int j = idx - 384*128; int i = j>>7, k = j&127; wt_out[k*128+i] = wout[j];
  } else {
    int j = idx - 384*128 - 128*128;     // 0..8191
    int k = j >> 7, c = j & 127;         // k<64 rows, c<128 cols
    float v = rad_w2[k*128 + c];
    unsigned int hb = f2bf(v);
    float hf = __uint_as_float(hb << 16);
    unsigned int lb = f2bf(v - hf);
    w2t_h[c*64 + k] = (unsigned short)hb;
    w2t_l[c*64 + k] = (unsigned short)lb;
  }
}

// ---------- counting sort of edges by destination ----------
__global__ void hist_kernel(const int* __restrict__ edge_index, int* __restrict__ counts){
  int e = blockIdx.x*blockDim.x + threadIdx.x;
  if (e < N_EDGES) atomicAdd(&counts[edge_index[N_EDGES + e]], 1);
}

__global__ void scan_kernel(const int* __restrict__ counts, int* __restrict__ offsets){
  __shared__ int buf[4096];
  int t = threadIdx.x; // 1024 threads
  for (int i=t;i<4096;i+=1024) buf[i]=counts[i];
  __syncthreads();
  for (int off=1; off<4096; off<<=1){
    int v[4];
    #pragma unroll
    for (int k=0;k<4;k++){ int i=t+k*1024; v[k] = (i>=off)?buf[i-off]:0; }
    __syncthreads();
    #pragma unroll
    for (int k=0;k<4;k++){ int i=t+k*1024; buf[i]+=v[k]; }
    __syncthreads();
  }
  for (int i=t;i<4096;i+=1024) offsets[i]=buf[i]-counts[i]; // exclusive
  if (t==0) offsets[4096]=buf[4095];
}

__global__ void scatter_kernel(const int* __restrict__ edge_index, const int* __restrict__ offsets,
                               int* __restrict__ cursor, int* __restrict__ edge_list){
  int e = blockIdx.x*blockDim.x + threadIdx.x;
  if (e < N_EDGES){
    int d = edge_index[N_EDGES + e];
    int pos = atomicAdd(&cursor[d], 1);
    edge_list[offsets[d] + pos] = e;
  }
}

// ---------- per-atom edge features via MFMA (r1@W2 as bf16 hi/lo GEMM) ----------
// 512 thr = 8 waves; wave (wm,wn2): 16-edge M-tile x 32-channel N-pair.
__global__ __launch_bounds__(512) void edge_F_kernel(
  const float* __restrict__ edge_vectors, const float* __restrict__ edge_lengths,
  const float* __restrict__ rad_w1, const float* __restrict__ rad_b1,
  const unsigned short* __restrict__ w2t_h, const unsigned short* __restrict__ w2t_l,
  const float* __restrict__ rad_b2,
  const int* __restrict__ offsets, const int* __restrict__ edge_list,
  float* __restrict__ Fp)
{
  const int a = blockIdx.x, tid = threadIdx.x;
  const int w = tid >> 6, lane = tid & 63;
  const int l15 = lane & 15, lg = lane >> 4;
  const int wm = w >> 2, wn2 = w & 3;

  __shared__ unsigned short W2h[128][72];   // 18 KB (pad 72 kills frag-read conflicts)
  __shared__ unsigned short W2l[128][72];   // 18 KB
  __shared__ unsigned short R1h[32][72];    // 4.5 KB
  __shared__ unsigned short R1l[32][72];    // 4.5 KB
  __shared__ float SH[32][9];               // 1.1 KB
  __shared__ float Fpart[2][128][9];        // 9 KB

  // stage W2^T planes ([128][64] u16 in global -> padded LDS)
  {
    const unsigned int* gh = (const unsigned int*)w2t_h;
    const unsigned int* gl = (const unsigned int*)w2t_l;
    for (int i = tid; i < 4096; i += 512){
      int c = i >> 5, kp = i & 31;
      *(unsigned int*)&W2h[c][kp*2] = gh[i];
      *(unsigned int*)&W2l[c][kp*2] = gl[i];
    }
  }

  float w1r[8];
  #pragma unroll
  for (int k=0;k<8;k++) w1r[k] = rad_w1[k*64 + lane];
  const float b1l = rad_b1[lane];
  const float b2c0 = rad_b2[wn2*32 + l15];
  const float b2c1 = rad_b2[wn2*32 + 16 + l15];

  float facc[2][9];
  #pragma unroll
  for (int nt=0;nt<2;nt++)
    #pragma unroll
    for (int j=0;j<9;j++) facc[nt][j]=0.f;

  const int beg = offsets[a], end = offsets[a+1];
  __syncthreads();   // W2 staged

  for (int t0 = beg; t0 < end; t0 += 32){
    // ---- phase 1: 4 edges per wave -> r1 hi/lo + sh into LDS ----
    #pragma unroll
    for (int s=0;s<4;s++){
      int es = w*4 + s;
      int ei = t0 + es;
      if (ei < end){
        int e = __builtin_amdgcn_readfirstlane(edge_list[ei]);
        float vx = edge_vectors[e*3], vy = edge_vectors[e*3+1], vz = edge_vectors[e*3+2];
        float d  = edge_lengths[e];
        float rn = sqrtf(vx*vx+vy*vy+vz*vz) + 1e-8f;
        float x = vx/rn, y = vy/rn, z = vz/rn;
        float rb = 0.f;
        if (lane < 8){
          float cut = 0.5f*(__cosf(d*PI6)+1.f)*(d<6.f?1.f:0.f);
          rb = __sinf(d*((float)(lane+1)*PI6))/d*cut;
        }
        float pre = b1l;
        #pragma unroll
        for (int k=0;k<8;k++) pre += bcastf(rb,k)*w1r[k];
        float r1 = silu_f(pre);
        unsigned int hb = f2bf(r1);
        float hf = __uint_as_float(hb<<16);
        unsigned int lb = f2bf(r1 - hf);
        R1h[es][lane] = (unsigned short)hb;
        R1l[es][lane] = (unsigned short)lb;
        if (lane < 9){
          float v = 1.f;
          if (lane==1) v=y; else if (lane==2) v=z; else if (lane==3) v=x;
          else if (lane==4) v=3.f*z*z-1.f; else if (lane==5) v=x*z;
          else if (lane==6) v=y*z; else if (lane==7) v=x*y; else if (lane==8) v=x*x-y*y;
          SH[es][lane]=v;
        }
      } else {
        R1h[es][lane]=0; R1l[es][lane]=0;   // avoid NaN garbage in frags
        if (lane<9) SH[es][lane]=0.f;       // zero contribution for tail slots
      }
    }
    __syncthreads();

    // ---- phase 2: 12 MFMA -> r2 tile; epilogue accumulates F ----
    bf16x8 Ah0 = ld8(&R1h[wm*16+l15][lg*8]);
    bf16x8 Ah1 = ld8(&R1h[wm*16+l15][32+lg*8]);
    bf16x8 Al0 = ld8(&R1l[wm*16+l15][lg*8]);
    bf16x8 Al1 = ld8(&R1l[wm*16+l15][32+lg*8]);
    f32x4 acc[2];
    #pragma unroll
    for (int nt=0;nt<2;nt++){
      int c16 = wn2*2+nt;
      bf16x8 Bh0 = ld8(&W2h[c16*16+l15][lg*8]);
      bf16x8 Bh1 = ld8(&W2h[c16*16+l15][32+lg*8]);
      bf16x8 Bl0 = ld8(&W2l[c16*16+l15][lg*8]);
      bf16x8 Bl1 = ld8(&W2l[c16*16+l15][32+lg*8]);
      f32x4 z = {0.f,0.f,0.f,0.f};
      z = __builtin_amdgcn_mfma_f32_16x16x32_bf16(Al0, Bh0, z,0,0,0);
      z = __builtin_amdgcn_mfma_f32_16x16x32_bf16(Al1, Bh1, z,0,0,0);
      z = __builtin_amdgcn_mfma_f32_16x16x32_bf16(Ah0, Bl0, z,0,0,0);
      z = __builtin_amdgcn_mfma_f32_16x16x32_bf16(Ah1, Bl1, z,0,0,0);
      z = __builtin_amdgcn_mfma_f32_16x16x32_bf16(Ah0, Bh0, z,0,0,0);
      z = __builtin_amdgcn_mfma_f32_16x16x32_bf16(Ah1, Bh1, z,0,0,0);
      acc[nt]=z;
    }
    #pragma unroll
    for (int r=0;r<4;r++){
      int es = wm*16 + lg*4 + r;
      float r20 = silu_f(acc[0][r] + b2c0);
      float r21 = silu_f(acc[1][r] + b2c1);
      #pragma unroll
      for (int j=0;j<9;j++){
        float sv = SH[es][j];
        facc[0][j] += r20*sv;
        facc[1][j] += r21*sv;
      }
    }
    __syncthreads();
  }

  // reduce partial F over lane groups (edges) then waves (wm)
  #pragma unroll
  for (int nt=0;nt<2;nt++)
    #pragma unroll
    for (int j=0;j<9;j++){
      float v = facc[nt][j];
      v += __shfl_xor(v, 16, 64);
      v += __shfl_xor(v, 32, 64);
      facc[nt][j]=v;
    }
  if (lane < 16){
    #pragma unroll
    for (int nt=0;nt<2;nt++){
      int c = wn2*32 + nt*16 + l15;
      #pragma unroll
      for (int j=0;j<9;j++) Fpart[wm][c][j] = facc[nt][j];
    }
  }
  __syncthreads();
  for (int i = tid; i < 1152; i += 512){
    int c = i & 127, j = i >> 7;
    Fp[j*(N_ATOMS*128) + a*128 + c] = Fpart[0][c][j] + Fpart[1][c][j];
  }
}

// ---------- node update: agg -> msg MLP -> qkv ; 8 atoms, 512 threads ----------
__global__ __launch_bounds__(512) void node_kernel(
  const int* __restrict__ atomic_numbers, const float* __restrict__ atom_embed,
  const float* __restrict__ tp_w, const float* __restrict__ tp_b,
  const float* __restrict__ msg_w1, const float* __restrict__ msg_b1,
  const float* __restrict__ msg_w2, const float* __restrict__ msg_b2,
  const float* __restrict__ wt_in, const float* __restrict__ attn_b_in,
  const int* __restrict__ offsets, const float* __restrict__ Fp,
  float* __restrict__ upd_out, float* __restrict__ qkv_out)
{
  const int a0 = blockIdx.x*8, tid = threadIdx.x;
  const int g = tid >> 7, o = tid & 127;
  __shared__ float red[4][8][128];   // 16 KB
  __shared__ float combs[8][192];
  __shared__ float hids[8][128];
  __shared__ float upds[8][128];

  float acc[8];
  #pragma unroll
  for (int a8=0;a8<8;a8++) acc[a8] = 0.f;

  const float4* Fp4 = (const float4*)Fp;
  for (int c4=g*8; c4<g*8+8; c4++){
    #pragma unroll
    for (int j=0;j<9;j++){
      float4 f[8];
      #pragma unroll
      for (int a8=0;a8<8;a8++) f[a8] = Fp4[j*(N_ATOMS*32) + (a0+a8)*32 + c4];
      #pragma unroll
      for (int cc=0;cc<4;cc++){
        int c = c4*4+cc;
        int row = (j==0)? c : (j<4 ? 128 + c*3 + (j-1) : 512 + c*5 + (j-4));
        float w = tp_w[row*128+o];
        #pragma unroll
        for (int a8=0;a8<8;a8++){
          float fv = (cc==0)?f[a8].x:(cc==1)?f[a8].y:(cc==2)?f[a8].z:f[a8].w;
          acc[a8] += fv*w;
        }
      }
    }
  }
  #pragma unroll
  for (int a8=0;a8<8;a8++) red[g][a8][o] = acc[a8];
  { int a8 = tid>>6, k = tid&63;
    combs[a8][k] = atom_embed[atomic_numbers[a0+a8]*64 + k]; }
  __syncthreads();
  if (g==0){
    const float tb = tp_b[o];
    #pragma unroll
    for (int a8=0;a8<8;a8++){
      float deg = (float)(offsets[a0+a8+1]-offsets[a0+a8]);
      combs[a8][64+o] = red[0][a8][o]+red[1][a8][o]+red[2][a8][o]+red[3][a8][o] + tb*deg;
    }
  }
  __syncthreads();

  const int aA = 2*g, aB = 2*g+1;
  {
    float hA = msg_b1[o], hB = hA;
    for (int k=0;k<192;k++){
      float w = msg_w1[k*128+o];
      hA += combs[aA][k]*w; hB += combs[aB][k]*w;
    }
    hids[aA][o] = silu_f(hA); hids[aB][o] = silu_f(hB);
  }
  __syncthreads();
  {
    float uA = msg_b2[o], uB = uA;
    for (int k=0;k<128;k++){
      float w = msg_w2[k*128+o];
      uA += hids[aA][k]*w; uB += hids[aB][k]*w;
    }
    upds[aA][o]=uA; upds[aB][o]=uB;
    upd_out[(a0+aA)*128+o]=uA; upd_out[(a0+aB)*128+o]=uB;
  }
  __syncthreads();
  for (int p=0;p<3;p++){
    float qA = attn_b_in[p*128+o], qB = qA;
    for (int k=0;k<128;k++){
      float w = wt_in[k*384 + p*128 + o];
      qA += upds[aA][k]*w; qB += upds[aB][k]*w;
    }
    qkv_out[(a0+aA)*384 + p*128 + o] = qA;
    qkv_out[(a0+aB)*384 + p*128 + o] = qB;
  }
}

// ---------- MFMA flash attention: 4 heads, N=4096, D=32, bf16 matmuls ----------
__global__ __launch_bounds__(256) void attn_kernel(const float* __restrict__ qkv, float* __restrict__ att){
  const int b = blockIdx.x;
  const int h = b >> 7, qt = b & 127;      // 4 heads, 128 q-tiles of 32
  const int tid = threadIdx.x;
  const int w = tid >> 6, lane = tid & 63;
  const int wq = w & 1, wk = w >> 1;       // query group, key half
  const int l15 = lane & 15, lg = lane >> 4;
  const int n0 = qt*32;

  __shared__ unsigned short Qs[32][36];
  __shared__ unsigned short Ks[2][2][64][36];
  __shared__ unsigned short Vt[2][2][32][66];
  __shared__ unsigned short Ps[8][16][68];
  __shared__ float MB[2][64][16];

  const float scale = 0.17677669529663687f; // 1/sqrt(32)

  {
    int qr = tid>>3, d4 = (tid&7)*4;
    const float4 qf = *(const float4*)(qkv + (size_t)(n0+qr)*384 + h*32 + d4);
    unsigned int* dst = (unsigned int*)&Qs[qr][d4];
    dst[0] = f2bf(qf.x*scale) | (f2bf(qf.y*scale)<<16);
    dst[1] = f2bf(qf.z*scale) | (f2bf(qf.w*scale)<<16);
  }

  const int hf = tid >> 7, u = tid & 127;
  const int skey = u >> 1, sd16 = (u & 1)*16;
  float4 kA,kB,kC,kD, vA,vB,vC,vD;

  #define LOADG(T) { \
    const float* kp = qkv + (size_t)(((hf*32+(T))*64 + skey))*384 + 128 + h*32 + sd16; \
    kA = *(const float4*)kp;        kB = *(const float4*)(kp+4); \
    kC = *(const float4*)(kp+8);    kD = *(const float4*)(kp+12); \
    const float* vp = kp + 128; \
    vA = *(const float4*)vp;        vB = *(const float4*)(vp+4); \
    vC = *(const float4*)(vp+8);    vD = *(const float4*)(vp+12); }

  #define WRITEL(BUF) { \
    unsigned int* kdst = (unsigned int*)&Ks[BUF][hf][skey][sd16]; \
    kdst[0]=f2bf(kA.x)|(f2bf(kA.y)<<16); kdst[1]=f2bf(kA.z)|(f2bf(kA.w)<<16); \
    kdst[2]=f2bf(kB.x)|(f2bf(kB.y)<<16); kdst[3]=f2bf(kB.z)|(f2bf(kB.w)<<16); \
    kdst[4]=f2bf(kC.x)|(f2bf(kC.y)<<16); kdst[5]=f2bf(kC.z)|(f2bf(kC.w)<<16); \
    kdst[6]=f2bf(kD.x)|(f2bf(kD.y)<<16); kdst[7]=f2bf(kD.z)|(f2bf(kD.w)<<16); \
    Vt[BUF][hf][sd16+ 0][skey]=(unsigned short)f2bf(vA.x); \
    Vt[BUF][hf][sd16+ 1][skey]=(unsigned short)f2bf(vA.y); \
    Vt[BUF][hf][sd16+ 2][skey]=(unsigned short)f2bf(vA.z); \
    Vt[BUF][hf][sd16+ 3][skey]=(unsigned short)f2bf(vA.w); \
    Vt[BUF][hf][sd16+ 4][skey]=(unsigned short)f2bf(vB.x); \
    Vt[BUF][hf][sd16+ 5][skey]=(unsigned short)f2bf(vB.y); \
    Vt[BUF][hf][sd16+ 6][skey]=(unsigned short)f2bf(vB.z); \
    Vt[BUF][hf][sd16+ 7][skey]=(unsigned short)f2bf(vB.w); \
    Vt[BUF][hf][sd16+ 8][skey]=(unsigned short)f2bf(vC.x); \
    Vt[BUF][hf][sd16+ 9][skey]=(unsigned short)f2bf(vC.y); \
    Vt[BUF][hf][sd16+10][skey]=(unsigned short)f2bf(vC.z); \
    Vt[BUF][hf][sd16+11][skey]=(unsigned short)f2bf(vC.w); \
    Vt[BUF][hf][sd16+12][skey]=(unsigned short)f2bf(vD.x); \
    Vt[BUF][hf][sd16+13][skey]=(unsigned short)f2bf(vD.y); \
    Vt[BUF][hf][sd16+14][skey]=(unsigned short)f2bf(vD.z); \
    Vt[BUF][hf][sd16+15][skey]=(unsigned short)f2bf(vD.w); }

  LOADG(0);
  WRITEL(0);
  __syncthreads();

  bf16x8 aQ = ld8(&Qs[wq*16 + l15][lg*8]);

  float m[4] = {-3e38f,-3e38f,-3e38f,-3e38f};
  float su[4] = {0.f,0.f,0.f,0.f};
  f32x4 oacc[2] = {{0.f,0.f,0.f,0.f},{0.f,0.f,0.f,0.f}};

  for (int t=0; t<32; t++){
    const int cur = t&1;
    if (t<31) LOADG(t+1);

    f32x4 s[4];
    #pragma unroll
    for (int n=0;n<4;n++){
      bf16x8 bK = ld8(&Ks[cur][wk][n*16+l15][lg*8]);
      f32x4 z = {0.f,0.f,0.f,0.f};
      s[n] = __builtin_amdgcn_mfma_f32_16x16x32_bf16(aQ, bK, z, 0,0,0);
    }

    float csc[4], psum[4];
    #pragma unroll
    for (int r=0;r<4;r++){
      float mloc = fmaxf(fmaxf(s[0][r], s[1][r]), fmaxf(s[2][r], s[3][r]));
      #pragma unroll
      for (int off=1; off<16; off<<=1) mloc = fmaxf(mloc, __shfl_xor(mloc, off, 64));
      float mn = fmaxf(m[r], mloc);
      csc[r] = __expf(m[r] - mn);
      m[r] = mn;
      psum[r] = 0.f;
    }
    #pragma unroll
    for (int n=0;n<4;n++){
      #pragma unroll
      for (int r=0;r<4;r++){
        float p = __expf(s[n][r] - m[r]);
        psum[r] += p;
        Ps[w][lg*4+r][n*16+l15] = (unsigned short)f2bf(p);
      }
    }
    #pragma unroll
    for (int r=0;r<4;r++){
      #pragma unroll
      for (int off=1; off<16; off<<=1) psum[r] += __shfl_xor(psum[r], off, 64);
      su[r] = su[r]*csc[r] + psum[r];
    }
    #pragma unroll
    for (int nd=0;nd<2;nd++){
      #pragma unroll
      for (int r=0;r<4;r++) oacc[nd][r] *= csc[r];
    }

    #pragma unroll
    for (int c=0;c<2;c++){
      bf16x8 aP = ld8(&Ps[w][l15][c*32 + lg*8]);
      #pragma unroll
      for (int nd=0;nd<2;nd++){
        bf16x8 bV = ld8(&Vt[cur][wk][nd*16+l15][c*32 + lg*8]);
        oacc[nd] = __builtin_amdgcn_mfma_f32_16x16x32_bf16(aP, bV, oacc[nd], 0,0,0);
      }
    }

    __syncthreads();
    if (t<31) WRITEL((t+1)&1);
    __syncthreads();
  }

  if (wk==1){
    #pragma unroll
    for (int r=0;r<4;r++){ MB[wq][lane][r] = m[r]; MB[wq][lane][4+r] = su[r]; }
    #pragma unroll
    for (int nd=0;nd<2;nd++)
      #pragma unroll
      for (int r=0;r<4;r++) MB[wq][lane][8+nd*4+r] = oacc[nd][r];
  }
  __syncthreads();
  if (wk==0){
    #pragma unroll
    for (int r=0;r<4;r++){
      float m1 = MB[wq][lane][r], s1 = MB[wq][lane][4+r];
      float mf = fmaxf(m[r], m1);
      float c0 = __expf(m[r]-mf), c1 = __expf(m1-mf);
      float stot = su[r]*c0 + s1*c1;
      float inv = 1.f/stot;
      #pragma unroll
      for (int nd=0;nd<2;nd++){
        float o = oacc[nd][r]*c0 + MB[wq][lane][8+nd*4+r]*c1;
        att[(size_t)(n0 + wq*16 + lg*4 + r)*128 + h*32 + nd*16 + l15] = o*inv;
      }
    }
  }
  #undef LOADG
  #undef WRITEL
}

// ---------- epilogue: 8 atoms, 512 threads, LDS-staged operands ----------
__global__ __launch_bounds__(512) void final_kernel(
  const float* __restrict__ att, const float* __restrict__ upd,
  const float* __restrict__ wt_out, const float* __restrict__ attn_b_out,
  const float* __restrict__ gate_w, const float* __restrict__ gate_b,
  const float* __restrict__ out_w, const float* __restrict__ out_b,
  float* __restrict__ out)
{
  const int a0 = blockIdx.x*8, tid = threadIdx.x;
  const int g = tid >> 7, o = tid & 127;
  __shared__ float att_s[8][128], upd_s[8][128], tmps[8][128];
  for (int i=tid; i<1024; i+=512){
    int a8 = i>>7, k = i&127;
    att_s[a8][k] = att[(a0+a8)*128+k];
    upd_s[a8][k] = upd[(a0+a8)*128+k];
  }
  __syncthreads();
  const int aA = 2*g, aB = 2*g+1;
  float a2A = attn_b_out[o], a2B = a2A;
  float gA = gate_b[o], gB = gA;
  for (int k=0;k<128;k++){
    float wa = wt_out[k*128+o];
    float wg = gate_w[k*128+o];
    a2A += att_s[aA][k]*wa; a2B += att_s[aB][k]*wa;
    gA  += upd_s[aA][k]*wg; gB  += upd_s[aB][k]*wg;
  }
  gA = sigmoid_f(gA); gB = sigmoid_f(gB);
  tmps[aA][o] = gA*a2A + (1.f-gA)*upd_s[aA][o];
  tmps[aB][o] = gB*a2B + (1.f-gB)*upd_s[aB][o];
  __syncthreads();
  float ouA = out_b[o], ouB = ouA;
  for (int k=0;k<128;k++){
    float w = out_w[k*128+o];
    ouA += tmps[aA][k]*w; ouB += tmps[aB][k]*w;
  }
  out[(a0+aA)*128+o] = ouA;
  out[(a0+aB)*128+o] = ouB;
}

extern "C" void kernel_launch(void* const* d_in, const int* in_sizes, int n_in,
                              void* d_out, int out_size, void* d_ws, size_t ws_size,
                              hipStream_t stream){
  const int*   atomic_numbers = (const int*)  d_in[0];
  const int*   edge_index     = (const int*)  d_in[2];
  const float* edge_vectors   = (const float*)d_in[3];
  const float* edge_lengths   = (const float*)d_in[4];
  const float* atom_embed     = (const float*)d_in[5];
  const float* rad_w1 = (const float*)d_in[6];
  const float* rad_b1 = (const float*)d_in[7];
  const float* rad_w2 = (const float*)d_in[8];
  const float* rad_b2 = (const float*)d_in[9];
  const float* tp_w   = (const float*)d_in[10];
  const float* tp_b   = (const float*)d_in[11];
  const float* msg_w1 = (const float*)d_in[12];
  const float* msg_b1 = (const float*)d_in[13];
  const float* msg_w2 = (const float*)d_in[14];
  const float* msg_b2 = (const float*)d_in[15];
  const float* attn_w_in  = (const float*)d_in[16];
  const float* attn_b_in  = (const float*)d_in[17];
  const float* attn_w_out = (const float*)d_in[18];
  const float* attn_b_out = (const float*)d_in[19];
  const float* gate_w = (const float*)d_in[20];
  const float* gate_b = (const float*)d_in[21];
  const float* out_w  = (const float*)d_in[22];
  const float* out_b  = (const float*)d_in[23];

  // workspace layout (bytes)
  char* ws = (char*)d_ws;
  int* counts    = (int*)(ws);             // [0, 16384)
  int* cursor    = (int*)(ws + 16384);     // [16384, 32768)
  int* offsets   = (int*)(ws + 32768);     // [32768, 49156)  4097 ints
  int* edge_list = (int*)(ws + 53248);     // [53248, 577536)
  float* wt_in   = (float*)(ws + 577536);  // 128x384
  float* wt_out  = (float*)(ws + 774144);  // 128x128
  float* Fp      = (float*)(ws + 839680);  // [9][4096*128] = 18.9 MB
  float* att     = (float*)(ws + 839680);  // aliases Fp (dead before attn)
  float* upd     = (float*)(ws + 19714048);// 2 MB
  float* qkv     = (float*)(ws + 21811200);// 6.3 MB  (end 28102656)
  // w2t planes alias upd: written by transpose (t0), read by edge_F (t5),
  // upd written by node (t6) AFTER edge_F completes -> no conflict.
  unsigned short* w2t_h = (unsigned short*)(ws + 19714048);  // 16 KB
  unsigned short* w2t_l = (unsigned short*)(ws + 19730432);  // 16 KB

  transpose_kernel<<<288, 256, 0, stream>>>(attn_w_in, attn_w_out, rad_w2,
      wt_in, wt_out, w2t_h, w2t_l);
  hipMemsetAsync(ws, 0, 32768, stream);  // counts + cursor
  hist_kernel<<<(N_EDGES+255)/256, 256, 0, stream>>>(edge_index, counts);
  scan_kernel<<<1, 1024, 0, stream>>>(counts, offsets);
  scatter_kernel<<<(N_EDGES+255)/256, 256, 0, stream>>>(edge_index, offsets, cursor, edge_list);
  edge_F_kernel<<<N_ATOMS, 512, 0, stream>>>(edge_vectors, edge_lengths,
      rad_w1, rad_b1, w2t_h, w2t_l, rad_b2, offsets, edge_list, Fp);
  node_kernel<<<N_ATOMS/8, 512, 0, stream>>>(atomic_numbers, atom_embed,
      tp_w, tp_b, msg_w1, msg_b1, msg_w2, msg_b2, wt_in, attn_b_in,
      offsets, Fp, upd, qkv);
  attn_kernel<<<512, 256, 0, stream>>>(qkv, att);
  final_kernel<<<N_ATOMS/8, 512, 0, stream>>>(att, upd, wt_out, attn_b_out,
      gate_w, gate_b, out_w, out_b, (float*)d_out);
}

// Round 11
// 279.382 us; speedup vs baseline: 1.5975x; 1.2124x over previous
//
#include <hip/hip_runtime.h>
#include <math.h>

#define N_ATOMS 4096
#define N_EDGES 131072
#define PI6 0.52359877559829887f

typedef __attribute__((ext_vector_type(8))) short bf16x8;
typedef __attribute__((ext_vector_type(4))) float f32x4;

#define MFMA(A,B,C) __builtin_amdgcn_mfma_f32_16x16x32_bf16((A),(B),(C),0,0,0)

__device__ __forceinline__ float silu_f(float x){ return x / (1.f + __expf(-x)); }
__device__ __forceinline__ float sigmoid_f(float x){ return 1.f / (1.f + __expf(-x)); }
__device__ __forceinline__ float bcastf(float v, int k){
  return __int_as_float(__builtin_amdgcn_readlane(__float_as_int(v), k));
}
__device__ __forceinline__ unsigned int f2bf(float f){
  unsigned int u = __float_as_uint(f);
  return (u + 0x7FFFu + ((u>>16)&1u)) >> 16;
}
__device__ __forceinline__ bf16x8 ld8(const unsigned short* p){
  union { unsigned int u[4]; bf16x8 v; } r;
  const unsigned int* q = (const unsigned int*)p;
  r.u[0]=q[0]; r.u[1]=q[1]; r.u[2]=q[2]; r.u[3]=q[3];
  return r.v;
}
__device__ __forceinline__ void split_store(float v, unsigned short* ph, unsigned short* pl){
  unsigned int hb = f2bf(v);
  *ph = (unsigned short)hb;
  *pl = (unsigned short)f2bf(v - __uint_as_float(hb<<16));
}

// ---------- prep: wt_out transpose (fp32) + all bf16 hi/lo weight planes ----------
__global__ __launch_bounds__(256) void prep_kernel(
  const float* __restrict__ attn_w_out, const float* __restrict__ rad_w2,
  const float* __restrict__ tp_w, const float* __restrict__ msg_w1,
  const float* __restrict__ msg_w2, const float* __restrict__ attn_w_in,
  float* __restrict__ wt_out,
  unsigned short* __restrict__ w2t_h, unsigned short* __restrict__ w2t_l,
  unsigned short* __restrict__ tpwT_h, unsigned short* __restrict__ tpwT_l,
  unsigned short* __restrict__ w1T_h, unsigned short* __restrict__ w1T_l,
  unsigned short* __restrict__ w2T_h, unsigned short* __restrict__ w2T_l,
  unsigned short* __restrict__ awin_h, unsigned short* __restrict__ awin_l)
{
  int idx = blockIdx.x*256 + threadIdx.x;
  if (idx < 16384){                       // wt_out: [128][128] transpose fp32
    int i = idx>>7, k = idx&127;
    wt_out[k*128+i] = attn_w_out[idx];
  } else if (idx < 24576){                // w2t: rad_w2^T hi/lo [128][64]
    int j = idx - 16384; int k = j>>7, c = j&127;
    split_store(rad_w2[k*128+c], &w2t_h[c*64+k], &w2t_l[c*64+k]);
  } else if (idx < 172032){               // tpwT: [128 col][1152 k] reordered
    int j = idx - 24576; int col = j&127, kk = j>>7;
    int jj = kk>>7, c = kk&127;
    int r = (jj==0)? c : (jj<4 ? 128 + c*3 + (jj-1) : 512 + c*5 + (jj-4));
    split_store(tp_w[r*128+col], &tpwT_h[col*1152+kk], &tpwT_l[col*1152+kk]);
  } else if (idx < 196608){               // w1T: [128][192]
    int j = idx - 172032; int col = j&127, k = j>>7;
    split_store(msg_w1[k*128+col], &w1T_h[col*192+k], &w1T_l[col*192+k]);
  } else if (idx < 212992){               // w2T: [128][128]
    int j = idx - 196608; int col = j&127, k = j>>7;
    split_store(msg_w2[k*128+col], &w2T_h[col*128+k], &w2T_l[col*128+k]);
  } else if (idx < 262144){               // awin: attn_w_in [384][128] as-is
    int j = idx - 212992;
    split_store(attn_w_in[j], &awin_h[j], &awin_l[j]);
  }
}

// ---------- counting sort of edges by destination ----------
__global__ void hist_kernel(const int* __restrict__ edge_index, int* __restrict__ counts){
  int e = blockIdx.x*blockDim.x + threadIdx.x;
  if (e < N_EDGES) atomicAdd(&counts[edge_index[N_EDGES + e]], 1);
}

__global__ void scan_kernel(const int* __restrict__ counts, int* __restrict__ offsets){
  __shared__ int buf[4096];
  int t = threadIdx.x; // 1024 threads
  for (int i=t;i<4096;i+=1024) buf[i]=counts[i];
  __syncthreads();
  for (int off=1; off<4096; off<<=1){
    int v[4];
    #pragma unroll
    for (int k=0;k<4;k++){ int i=t+k*1024; v[k] = (i>=off)?buf[i-off]:0; }
    __syncthreads();
    #pragma unroll
    for (int k=0;k<4;k++){ int i=t+k*1024; buf[i]+=v[k]; }
    __syncthreads();
  }
  for (int i=t;i<4096;i+=1024) offsets[i]=buf[i]-counts[i]; // exclusive
  if (t==0) offsets[4096]=buf[4095];
}

__global__ void scatter_kernel(const int* __restrict__ edge_index, const int* __restrict__ offsets,
                               int* __restrict__ cursor, int* __restrict__ edge_list){
  int e = blockIdx.x*blockDim.x + threadIdx.x;
  if (e < N_EDGES){
    int d = edge_index[N_EDGES + e];
    int pos = atomicAdd(&cursor[d], 1);
    edge_list[offsets[d] + pos] = e;
  }
}

// ---------- per-atom edge features via MFMA; F emitted as bf16 hi/lo planes ----------
__global__ __launch_bounds__(512) void edge_F_kernel(
  const float* __restrict__ edge_vectors, const float* __restrict__ edge_lengths,
  const float* __restrict__ rad_w1, const float* __restrict__ rad_b1,
  const unsigned short* __restrict__ w2t_h, const unsigned short* __restrict__ w2t_l,
  const float* __restrict__ rad_b2,
  const int* __restrict__ offsets, const int* __restrict__ edge_list,
  unsigned short* __restrict__ Fh, unsigned short* __restrict__ Fl)
{
  const int a = blockIdx.x, tid = threadIdx.x;
  const int w = tid >> 6, lane = tid & 63;
  const int l15 = lane & 15, lg = lane >> 4;
  const int wm = w >> 2, wn2 = w & 3;

  __shared__ unsigned short W2h[128][72];
  __shared__ unsigned short W2l[128][72];
  __shared__ unsigned short R1h[32][72];
  __shared__ unsigned short R1l[32][72];
  __shared__ float SH[32][9];
  __shared__ float Fpart[2][128][9];

  {
    const unsigned int* gh = (const unsigned int*)w2t_h;
    const unsigned int* gl = (const unsigned int*)w2t_l;
    for (int i = tid; i < 4096; i += 512){
      int c = i >> 5, kp = i & 31;
      *(unsigned int*)&W2h[c][kp*2] = gh[i];
      *(unsigned int*)&W2l[c][kp*2] = gl[i];
    }
  }

  float w1r[8];
  #pragma unroll
  for (int k=0;k<8;k++) w1r[k] = rad_w1[k*64 + lane];
  const float b1l = rad_b1[lane];
  const float b2c0 = rad_b2[wn2*32 + l15];
  const float b2c1 = rad_b2[wn2*32 + 16 + l15];

  float facc[2][9];
  #pragma unroll
  for (int nt=0;nt<2;nt++)
    #pragma unroll
    for (int j=0;j<9;j++) facc[nt][j]=0.f;

  const int beg = offsets[a], end = offsets[a+1];
  __syncthreads();

  for (int t0 = beg; t0 < end; t0 += 32){
    #pragma unroll
    for (int s=0;s<4;s++){
      int es = w*4 + s;
      int ei = t0 + es;
      if (ei < end){
        int e = __builtin_amdgcn_readfirstlane(edge_list[ei]);
        float vx = edge_vectors[e*3], vy = edge_vectors[e*3+1], vz = edge_vectors[e*3+2];
        float d  = edge_lengths[e];
        float rn = sqrtf(vx*vx+vy*vy+vz*vz) + 1e-8f;
        float x = vx/rn, y = vy/rn, z = vz/rn;
        float rb = 0.f;
        if (lane < 8){
          float cut = 0.5f*(__cosf(d*PI6)+1.f)*(d<6.f?1.f:0.f);
          rb = __sinf(d*((float)(lane+1)*PI6))/d*cut;
        }
        float pre = b1l;
        #pragma unroll
        for (int k=0;k<8;k++) pre += bcastf(rb,k)*w1r[k];
        float r1 = silu_f(pre);
        split_store(r1, &R1h[es][lane], &R1l[es][lane]);
        if (lane < 9){
          float v = 1.f;
          if (lane==1) v=y; else if (lane==2) v=z; else if (lane==3) v=x;
          else if (lane==4) v=3.f*z*z-1.f; else if (lane==5) v=x*z;
          else if (lane==6) v=y*z; else if (lane==7) v=x*y; else if (lane==8) v=x*x-y*y;
          SH[es][lane]=v;
        }
      } else {
        R1h[es][lane]=0; R1l[es][lane]=0;
        if (lane<9) SH[es][lane]=0.f;
      }
    }
    __syncthreads();

    bf16x8 Ah0 = ld8(&R1h[wm*16+l15][lg*8]);
    bf16x8 Ah1 = ld8(&R1h[wm*16+l15][32+lg*8]);
    bf16x8 Al0 = ld8(&R1l[wm*16+l15][lg*8]);
    bf16x8 Al1 = ld8(&R1l[wm*16+l15][32+lg*8]);
    f32x4 acc[2];
    #pragma unroll
    for (int nt=0;nt<2;nt++){
      int c16 = wn2*2+nt;
      bf16x8 Bh0 = ld8(&W2h[c16*16+l15][lg*8]);
      bf16x8 Bh1 = ld8(&W2h[c16*16+l15][32+lg*8]);
      bf16x8 Bl0 = ld8(&W2l[c16*16+l15][lg*8]);
      bf16x8 Bl1 = ld8(&W2l[c16*16+l15][32+lg*8]);
      f32x4 z = {0.f,0.f,0.f,0.f};
      z = MFMA(Al0, Bh0, z);
      z = MFMA(Al1, Bh1, z);
      z = MFMA(Ah0, Bl0, z);
      z = MFMA(Ah1, Bl1, z);
      z = MFMA(Ah0, Bh0, z);
      z = MFMA(Ah1, Bh1, z);
      acc[nt]=z;
    }
    #pragma unroll
    for (int r=0;r<4;r++){
      int es = wm*16 + lg*4 + r;
      float r20 = silu_f(acc[0][r] + b2c0);
      float r21 = silu_f(acc[1][r] + b2c1);
      #pragma unroll
      for (int j=0;j<9;j++){
        float sv = SH[es][j];
        facc[0][j] += r20*sv;
        facc[1][j] += r21*sv;
      }
    }
    __syncthreads();
  }

  #pragma unroll
  for (int nt=0;nt<2;nt++)
    #pragma unroll
    for (int j=0;j<9;j++){
      float v = facc[nt][j];
      v += __shfl_xor(v, 16, 64);
      v += __shfl_xor(v, 32, 64);
      facc[nt][j]=v;
    }
  if (lane < 16){
    #pragma unroll
    for (int nt=0;nt<2;nt++){
      int c = wn2*32 + nt*16 + l15;
      #pragma unroll
      for (int j=0;j<9;j++) Fpart[wm][c][j] = facc[nt][j];
    }
  }
  __syncthreads();
  for (int i = tid; i < 1152; i += 512){
    int c = i & 127, j = i >> 7;
    float v = Fpart[0][c][j] + Fpart[1][c][j];
    size_t o = (size_t)j*(N_ATOMS*128) + a*128 + c;
    split_store(v, &Fh[o], &Fl[o]);
  }
}

// ---------- fused node: agg GEMM + msg MLP + qkv, all MFMA hi/lo ----------
// 16 atoms/block, 512 thr = 8 waves; wave w owns 16 output cols per layer.
__global__ __launch_bounds__(512) void node_kernel(
  const int* __restrict__ atomic_numbers, const float* __restrict__ atom_embed,
  const unsigned short* __restrict__ Fh, const unsigned short* __restrict__ Fl,
  const unsigned short* __restrict__ tpwT_h, const unsigned short* __restrict__ tpwT_l,
  const float* __restrict__ tp_b, const int* __restrict__ offsets,
  const unsigned short* __restrict__ w1T_h, const unsigned short* __restrict__ w1T_l,
  const float* __restrict__ msg_b1,
  const unsigned short* __restrict__ w2T_h, const unsigned short* __restrict__ w2T_l,
  const float* __restrict__ msg_b2,
  const unsigned short* __restrict__ awin_h, const unsigned short* __restrict__ awin_l,
  const float* __restrict__ attn_b_in,
  float* __restrict__ upd_out, float* __restrict__ qkv_out)
{
  const int a0 = blockIdx.x*16, tid = threadIdx.x;
  const int w = tid>>6, lane = tid&63, l15 = lane&15, lg = lane>>4;

  __shared__ unsigned short Ch[16][200], Cl[16][200];   // comb (192 + pad)
  __shared__ unsigned short Hh[16][136], Hl[16][136];   // hid
  __shared__ unsigned short Uh[16][136], Ul[16][136];   // upd

  // stage embed into comb cols 0..63
  for (int i=tid; i<1024; i+=512){
    int a16=i>>6, k=i&63;
    float v = atom_embed[atomic_numbers[a0+a16]*64+k];
    split_store(v, &Ch[a16][k], &Cl[a16][k]);
  }

  // agg GEMM: C[16 atoms][128] = F[16][1152] @ tpwT^T ; wave w -> cols w*16..+16
  {
    f32x4 z = {0.f,0.f,0.f,0.f};
    for (int ch=0; ch<36; ch++){
      int k0=ch*32, j=k0>>7, c0=k0&127;
      size_t aoff = (size_t)j*(N_ATOMS*128) + (size_t)(a0+l15)*128 + c0 + lg*8;
      bf16x8 Ah=ld8(Fh+aoff), Al=ld8(Fl+aoff);
      size_t boff = (size_t)(w*16+l15)*1152 + k0 + lg*8;
      bf16x8 Bh=ld8(tpwT_h+boff), Bl=ld8(tpwT_l+boff);
      z = MFMA(Ah,Bl,z); z = MFMA(Al,Bh,z); z = MFMA(Ah,Bh,z);
    }
    int col = w*16+l15;
    float tb = tp_b[col];
    #pragma unroll
    for (int r=0;r<4;r++){
      int row = lg*4+r, arow = a0+row;
      float deg = (float)(offsets[arow+1]-offsets[arow]);
      float v = z[r] + tb*deg;
      split_store(v, &Ch[row][64+col], &Cl[row][64+col]);
    }
  }
  __syncthreads();

  // msg1: hid = silu(comb @ msg_w1 + b1)
  {
    f32x4 z = {0.f,0.f,0.f,0.f};
    #pragma unroll
    for (int ch=0; ch<6; ch++){
      int k0=ch*32;
      bf16x8 Ah=ld8(&Ch[l15][k0+lg*8]), Al=ld8(&Cl[l15][k0+lg*8]);
      size_t boff=(size_t)(w*16+l15)*192 + k0 + lg*8;
      bf16x8 Bh=ld8(w1T_h+boff), Bl=ld8(w1T_l+boff);
      z = MFMA(Ah,Bl,z); z = MFMA(Al,Bh,z); z = MFMA(Ah,Bh,z);
    }
    int col = w*16+l15;
    float mb = msg_b1[col];
    #pragma unroll
    for (int r=0;r<4;r++){
      int row = lg*4+r;
      float v = silu_f(z[r]+mb);
      split_store(v, &Hh[row][col], &Hl[row][col]);
    }
  }
  __syncthreads();

  // msg2: upd = hid @ msg_w2 + b2  (fp32 out + hi/lo to LDS)
  {
    f32x4 z = {0.f,0.f,0.f,0.f};
    #pragma unroll
    for (int ch=0; ch<4; ch++){
      int k0=ch*32;
      bf16x8 Ah=ld8(&Hh[l15][k0+lg*8]), Al=ld8(&Hl[l15][k0+lg*8]);
      size_t boff=(size_t)(w*16+l15)*128 + k0 + lg*8;
      bf16x8 Bh=ld8(w2T_h+boff), Bl=ld8(w2T_l+boff);
      z = MFMA(Ah,Bl,z); z = MFMA(Al,Bh,z); z = MFMA(Ah,Bh,z);
    }
    int col = w*16+l15;
    float mb = msg_b2[col];
    #pragma unroll
    for (int r=0;r<4;r++){
      int row = lg*4+r;
      float v = z[r]+mb;
      upd_out[(size_t)(a0+row)*128 + col] = v;
      split_store(v, &Uh[row][col], &Ul[row][col]);
    }
  }
  __syncthreads();

  // qkv: upd @ attn_w_in^T + b ; wave w -> 3 col-tiles
  #pragma unroll
  for (int t3=0; t3<3; t3++){
    f32x4 z = {0.f,0.f,0.f,0.f};
    int col = (w*3+t3)*16 + l15;
    #pragma unroll
    for (int ch=0; ch<4; ch++){
      int k0=ch*32;
      bf16x8 Ah=ld8(&Uh[l15][k0+lg*8]), Al=ld8(&Ul[l15][k0+lg*8]);
      size_t boff=(size_t)col*128 + k0 + lg*8;
      bf16x8 Bh=ld8(awin_h+boff), Bl=ld8(awin_l+boff);
      z = MFMA(Ah,Bl,z); z = MFMA(Al,Bh,z); z = MFMA(Ah,Bh,z);
    }
    float ab = attn_b_in[col];
    #pragma unroll
    for (int r=0;r<4;r++){
      int row = lg*4+r;
      qkv_out[(size_t)(a0+row)*384 + col] = z[r]+ab;
    }
  }
}

// ---------- MFMA flash attention: 4 heads, N=4096, D=32, bf16 matmuls ----------
__global__ __launch_bounds__(256) void attn_kernel(const float* __restrict__ qkv, float* __restrict__ att){
  const int b = blockIdx.x;
  const int h = b >> 7, qt = b & 127;
  const int tid = threadIdx.x;
  const int w = tid >> 6, lane = tid & 63;
  const int wq = w & 1, wk = w >> 1;
  const int l15 = lane & 15, lg = lane >> 4;
  const int n0 = qt*32;

  __shared__ unsigned short Qs[32][36];
  __shared__ unsigned short Ks[2][2][64][36];
  __shared__ unsigned short Vt[2][2][32][66];
  __shared__ unsigned short Ps[8][16][68];
  __shared__ float MB[2][64][16];

  const float scale = 0.17677669529663687f;

  {
    int qr = tid>>3, d4 = (tid&7)*4;
    const float4 qf = *(const float4*)(qkv + (size_t)(n0+qr)*384 + h*32 + d4);
    unsigned int* dst = (unsigned int*)&Qs[qr][d4];
    dst[0] = f2bf(qf.x*scale) | (f2bf(qf.y*scale)<<16);
    dst[1] = f2bf(qf.z*scale) | (f2bf(qf.w*scale)<<16);
  }

  const int hf = tid >> 7, u = tid & 127;
  const int skey = u >> 1, sd16 = (u & 1)*16;
  float4 kA,kB,kC,kD, vA,vB,vC,vD;

  #define LOADG(T) { \
    const float* kp = qkv + (size_t)(((hf*32+(T))*64 + skey))*384 + 128 + h*32 + sd16; \
    kA = *(const float4*)kp;        kB = *(const float4*)(kp+4); \
    kC = *(const float4*)(kp+8);    kD = *(const float4*)(kp+12); \
    const float* vp = kp + 128; \
    vA = *(const float4*)vp;        vB = *(const float4*)(vp+4); \
    vC = *(const float4*)(vp+8);    vD = *(const float4*)(vp+12); }

  #define WRITEL(BUF) { \
    unsigned int* kdst = (unsigned int*)&Ks[BUF][hf][skey][sd16]; \
    kdst[0]=f2bf(kA.x)|(f2bf(kA.y)<<16); kdst[1]=f2bf(kA.z)|(f2bf(kA.w)<<16); \
    kdst[2]=f2bf(kB.x)|(f2bf(kB.y)<<16); kdst[3]=f2bf(kB.z)|(f2bf(kB.w)<<16); \
    kdst[4]=f2bf(kC.x)|(f2bf(kC.y)<<16); kdst[5]=f2bf(kC.z)|(f2bf(kC.w)<<16); \
    kdst[6]=f2bf(kD.x)|(f2bf(kD.y)<<16); kdst[7]=f2bf(kD.z)|(f2bf(kD.w)<<16); \
    Vt[BUF][hf][sd16+ 0][skey]=(unsigned short)f2bf(vA.x); \
    Vt[BUF][hf][sd16+ 1][skey]=(unsigned short)f2bf(vA.y); \
    Vt[BUF][hf][sd16+ 2][skey]=(unsigned short)f2bf(vA.z); \
    Vt[BUF][hf][sd16+ 3][skey]=(unsigned short)f2bf(vA.w); \
    Vt[BUF][hf][sd16+ 4][skey]=(unsigned short)f2bf(vB.x); \
    Vt[BUF][hf][sd16+ 5][skey]=(unsigned short)f2bf(vB.y); \
    Vt[BUF][hf][sd16+ 6][skey]=(unsigned short)f2bf(vB.z); \
    Vt[BUF][hf][sd16+ 7][skey]=(unsigned short)f2bf(vB.w); \
    Vt[BUF][hf][sd16+ 8][skey]=(unsigned short)f2bf(vC.x); \
    Vt[BUF][hf][sd16+ 9][skey]=(unsigned short)f2bf(vC.y); \
    Vt[BUF][hf][sd16+10][skey]=(unsigned short)f2bf(vC.z); \
    Vt[BUF][hf][sd16+11][skey]=(unsigned short)f2bf(vC.w); \
    Vt[BUF][hf][sd16+12][skey]=(unsigned short)f2bf(vD.x); \
    Vt[BUF][hf][sd16+13][skey]=(unsigned short)f2bf(vD.y); \
    Vt[BUF][hf][sd16+14][skey]=(unsigned short)f2bf(vD.z); \
    Vt[BUF][hf][sd16+15][skey]=(unsigned short)f2bf(vD.w); }

  LOADG(0);
  WRITEL(0);
  __syncthreads();

  bf16x8 aQ = ld8(&Qs[wq*16 + l15][lg*8]);

  float m[4] = {-3e38f,-3e38f,-3e38f,-3e38f};
  float su[4] = {0.f,0.f,0.f,0.f};
  f32x4 oacc[2] = {{0.f,0.f,0.f,0.f},{0.f,0.f,0.f,0.f}};

  for (int t=0; t<32; t++){
    const int cur = t&1;
    if (t<31) LOADG(t+1);

    f32x4 s[4];
    #pragma unroll
    for (int n=0;n<4;n++){
      bf16x8 bK = ld8(&Ks[cur][wk][n*16+l15][lg*8]);
      f32x4 z = {0.f,0.f,0.f,0.f};
      s[n] = MFMA(aQ, bK, z);
    }

    float csc[4], psum[4];
    #pragma unroll
    for (int r=0;r<4;r++){
      float mloc = fmaxf(fmaxf(s[0][r], s[1][r]), fmaxf(s[2][r], s[3][r]));
      #pragma unroll
      for (int off=1; off<16; off<<=1) mloc = fmaxf(mloc, __shfl_xor(mloc, off, 64));
      float mn = fmaxf(m[r], mloc);
      csc[r] = __expf(m[r] - mn);
      m[r] = mn;
      psum[r] = 0.f;
    }
    #pragma unroll
    for (int n=0;n<4;n++){
      #pragma unroll
      for (int r=0;r<4;r++){
        float p = __expf(s[n][r] - m[r]);
        psum[r] += p;
        Ps[w][lg*4+r][n*16+l15] = (unsigned short)f2bf(p);
      }
    }
    #pragma unroll
    for (int r=0;r<4;r++){
      #pragma unroll
      for (int off=1; off<16; off<<=1) psum[r] += __shfl_xor(psum[r], off, 64);
      su[r] = su[r]*csc[r] + psum[r];
    }
    #pragma unroll
    for (int nd=0;nd<2;nd++){
      #pragma unroll
      for (int r=0;r<4;r++) oacc[nd][r] *= csc[r];
    }

    #pragma unroll
    for (int c=0;c<2;c++){
      bf16x8 aP = ld8(&Ps[w][l15][c*32 + lg*8]);
      #pragma unroll
      for (int nd=0;nd<2;nd++){
        bf16x8 bV = ld8(&Vt[cur][wk][nd*16+l15][c*32 + lg*8]);
        oacc[nd] = MFMA(aP, bV, oacc[nd]);
      }
    }

    __syncthreads();
    if (t<31) WRITEL((t+1)&1);
    __syncthreads();
  }

  if (wk==1){
    #pragma unroll
    for (int r=0;r<4;r++){ MB[wq][lane][r] = m[r]; MB[wq][lane][4+r] = su[r]; }
    #pragma unroll
    for (int nd=0;nd<2;nd++)
      #pragma unroll
      for (int r=0;r<4;r++) MB[wq][lane][8+nd*4+r] = oacc[nd][r];
  }
  __syncthreads();
  if (wk==0){
    #pragma unroll
    for (int r=0;r<4;r++){
      float m1 = MB[wq][lane][r], s1 = MB[wq][lane][4+r];
      float mf = fmaxf(m[r], m1);
      float c0 = __expf(m[r]-mf), c1 = __expf(m1-mf);
      float stot = su[r]*c0 + s1*c1;
      float inv = 1.f/stot;
      #pragma unroll
      for (int nd=0;nd<2;nd++){
        float o = oacc[nd][r]*c0 + MB[wq][lane][8+nd*4+r]*c1;
        att[(size_t)(n0 + wq*16 + lg*4 + r)*128 + h*32 + nd*16 + l15] = o*inv;
      }
    }
  }
  #undef LOADG
  #undef WRITEL
}

// ---------- epilogue: 8 atoms, 512 threads, LDS-staged operands ----------
__global__ __launch_bounds__(512) void final_kernel(
  const float* __restrict__ att, const float* __restrict__ upd,
  const float* __restrict__ wt_out, const float* __restrict__ attn_b_out,
  const float* __restrict__ gate_w, const float* __restrict__ gate_b,
  const float* __restrict__ out_w, const float* __restrict__ out_b,
  float* __restrict__ out)
{
  const int a0 = blockIdx.x*8, tid = threadIdx.x;
  const int g = tid >> 7, o = tid & 127;
  __shared__ float att_s[8][128], upd_s[8][128], tmps[8][128];
  for (int i=tid; i<1024; i+=512){
    int a8 = i>>7, k = i&127;
    att_s[a8][k] = att[(a0+a8)*128+k];
    upd_s[a8][k] = upd[(a0+a8)*128+k];
  }
  __syncthreads();
  const int aA = 2*g, aB = 2*g+1;
  float a2A = attn_b_out[o], a2B = a2A;
  float gA = gate_b[o], gB = gA;
  for (int k=0;k<128;k++){
    float wa = wt_out[k*128+o];
    float wg = gate_w[k*128+o];
    a2A += att_s[aA][k]*wa; a2B += att_s[aB][k]*wa;
    gA  += upd_s[aA][k]*wg; gB  += upd_s[aB][k]*wg;
  }
  gA = sigmoid_f(gA); gB = sigmoid_f(gB);
  tmps[aA][o] = gA*a2A + (1.f-gA)*upd_s[aA][o];
  tmps[aB][o] = gB*a2B + (1.f-gB)*upd_s[aB][o];
  __syncthreads();
  float ouA = out_b[o], ouB = ouA;
  for (int k=0;k<128;k++){
    float w = out_w[k*128+o];
    ouA += tmps[aA][k]*w; ouB += tmps[aB][k]*w;
  }
  out[(a0+aA)*128+o] = ouA;
  out[(a0+aB)*128+o] = ouB;
}

extern "C" void kernel_launch(void* const* d_in, const int* in_sizes, int n_in,
                              void* d_out, int out_size, void* d_ws, size_t ws_size,
                              hipStream_t stream){
  const int*   atomic_numbers = (const int*)  d_in[0];
  const int*   edge_index     = (const int*)  d_in[2];
  const float* edge_vectors   = (const float*)d_in[3];
  const float* edge_lengths   = (const float*)d_in[4];
  const float* atom_embed     = (const float*)d_in[5];
  const float* rad_w1 = (const float*)d_in[6];
  const float* rad_b1 = (const float*)d_in[7];
  const float* rad_w2 = (const float*)d_in[8];
  const float* rad_b2 = (const float*)d_in[9];
  const float* tp_w   = (const float*)d_in[10];
  const float* tp_b   = (const float*)d_in[11];
  const float* msg_w1 = (const float*)d_in[12];
  const float* msg_b1 = (const float*)d_in[13];
  const float* msg_w2 = (const float*)d_in[14];
  const float* msg_b2 = (const float*)d_in[15];
  const float* attn_w_in  = (const float*)d_in[16];
  const float* attn_b_in  = (const float*)d_in[17];
  const float* attn_w_out = (const float*)d_in[18];
  const float* attn_b_out = (const float*)d_in[19];
  const float* gate_w = (const float*)d_in[20];
  const float* gate_b = (const float*)d_in[21];
  const float* out_w  = (const float*)d_in[22];
  const float* out_b  = (const float*)d_in[23];

  // workspace layout (bytes)
  char* ws = (char*)d_ws;
  int* counts    = (int*)(ws);                       // [0,16384)
  int* cursor    = (int*)(ws + 16384);               // [16384,32768)
  int* offsets   = (int*)(ws + 32768);               // [32768,49156)
  int* edge_list = (int*)(ws + 53248);               // [53248,577536)
  float* wt_out  = (float*)(ws + 577536);            // [577536,643072)
  unsigned short* w2t_h  = (unsigned short*)(ws + 643072);   // 16 KB
  unsigned short* w2t_l  = (unsigned short*)(ws + 659456);   // 16 KB
  unsigned short* tpwT_h = (unsigned short*)(ws + 675840);   // 288 KB
  unsigned short* tpwT_l = (unsigned short*)(ws + 970752);   // 288 KB
  unsigned short* w1T_h  = (unsigned short*)(ws + 1265664);  // 48 KB
  unsigned short* w1T_l  = (unsigned short*)(ws + 1314816);  // 48 KB
  unsigned short* w2T_h  = (unsigned short*)(ws + 1363968);  // 32 KB
  unsigned short* w2T_l  = (unsigned short*)(ws + 1396736);  // 32 KB
  unsigned short* awin_h = (unsigned short*)(ws + 1429504);  // 96 KB
  unsigned short* awin_l = (unsigned short*)(ws + 1527808);  // 96 KB
  unsigned short* Fbf_h  = (unsigned short*)(ws + 1626112);  // 9.44 MB
  unsigned short* Fbf_l  = (unsigned short*)(ws + 11063296); // 9.44 MB
  float* att     = (float*)(ws + 1626112);           // aliases Fbf_h (dead after node)
  float* upd     = (float*)(ws + 20500480);          // 2 MB
  float* qkv     = (float*)(ws + 22597632);          // 6.3 MB (end 28889088)

  prep_kernel<<<1024, 256, 0, stream>>>(attn_w_out, rad_w2, tp_w, msg_w1, msg_w2, attn_w_in,
      wt_out, w2t_h, w2t_l, tpwT_h, tpwT_l, w1T_h, w1T_l, w2T_h, w2T_l, awin_h, awin_l);
  hipMemsetAsync(ws, 0, 32768, stream);  // counts + cursor
  hist_kernel<<<(N_EDGES+255)/256, 256, 0, stream>>>(edge_index, counts);
  scan_kernel<<<1, 1024, 0, stream>>>(counts, offsets);
  scatter_kernel<<<(N_EDGES+255)/256, 256, 0, stream>>>(edge_index, offsets, cursor, edge_list);
  edge_F_kernel<<<N_ATOMS, 512, 0, stream>>>(edge_vectors, edge_lengths,
      rad_w1, rad_b1, w2t_h, w2t_l, rad_b2, offsets, edge_list, Fbf_h, Fbf_l);
  node_kernel<<<N_ATOMS/16, 512, 0, stream>>>(atomic_numbers, atom_embed,
      Fbf_h, Fbf_l, tpwT_h, tpwT_l, tp_b, offsets,
      w1T_h, w1T_l, msg_b1, w2T_h, w2T_l, msg_b2, awin_h, awin_l, attn_b_in,
      upd, qkv);
  attn_kernel<<<512, 256, 0, stream>>>(qkv, att);
  final_kernel<<<N_ATOMS/8, 512, 0, stream>>>(att, upd, wt_out, attn_b_out,
      gate_w, gate_b, out_w, out_b, (float*)d_out);
}

// Round 12
// 247.114 us; speedup vs baseline: 1.8061x; 1.1306x over previous
//
#include <hip/hip_runtime.h>
#include <math.h>

#define N_ATOMS 4096
#define N_EDGES 131072
#define PI6 0.52359877559829887f

typedef __attribute__((ext_vector_type(8))) short bf16x8;
typedef __attribute__((ext_vector_type(4))) float f32x4;

#define MFMA(A,B,C) __builtin_amdgcn_mfma_f32_16x16x32_bf16((A),(B),(C),0,0,0)

__device__ __forceinline__ float silu_f(float x){ return x / (1.f + __expf(-x)); }
__device__ __forceinline__ float sigmoid_f(float x){ return 1.f / (1.f + __expf(-x)); }
__device__ __forceinline__ unsigned int f2bf(float f){
  unsigned int u = __float_as_uint(f);
  return (u + 0x7FFFu + ((u>>16)&1u)) >> 16;
}
__device__ __forceinline__ bf16x8 ld8(const unsigned short* p){
  union { unsigned int u[4]; bf16x8 v; } r;
  const unsigned int* q = (const unsigned int*)p;
  r.u[0]=q[0]; r.u[1]=q[1]; r.u[2]=q[2]; r.u[3]=q[3];
  return r.v;
}
__device__ __forceinline__ void split_store(float v, unsigned short* ph, unsigned short* pl){
  unsigned int hb = f2bf(v);
  *ph = (unsigned short)hb;
  *pl = (unsigned short)f2bf(v - __uint_as_float(hb<<16));
}

// ---------- prep: wt_out transpose (fp32) + all bf16 hi/lo weight planes ----------
__global__ __launch_bounds__(256) void prep_kernel(
  const float* __restrict__ attn_w_out, const float* __restrict__ rad_w2,
  const float* __restrict__ tp_w, const float* __restrict__ msg_w1,
  const float* __restrict__ msg_w2, const float* __restrict__ attn_w_in,
  float* __restrict__ wt_out,
  unsigned short* __restrict__ w2t_h, unsigned short* __restrict__ w2t_l,
  unsigned short* __restrict__ tpwT_h, unsigned short* __restrict__ tpwT_l,
  unsigned short* __restrict__ w1T_h, unsigned short* __restrict__ w1T_l,
  unsigned short* __restrict__ w2T_h, unsigned short* __restrict__ w2T_l,
  unsigned short* __restrict__ awin_h, unsigned short* __restrict__ awin_l)
{
  int idx = blockIdx.x*256 + threadIdx.x;
  if (idx < 16384){                       // wt_out: [128][128] transpose fp32
    int i = idx>>7, k = idx&127;
    wt_out[k*128+i] = attn_w_out[idx];
  } else if (idx < 24576){                // w2t: rad_w2^T hi/lo [128][64]
    int j = idx - 16384; int k = j>>7, c = j&127;
    split_store(rad_w2[k*128+c], &w2t_h[c*64+k], &w2t_l[c*64+k]);
  } else if (idx < 172032){               // tpwT: [128 col][1152 k] reordered
    int j = idx - 24576; int col = j&127, kk = j>>7;
    int jj = kk>>7, c = kk&127;
    int r = (jj==0)? c : (jj<4 ? 128 + c*3 + (jj-1) : 512 + c*5 + (jj-4));
    split_store(tp_w[r*128+col], &tpwT_h[col*1152+kk], &tpwT_l[col*1152+kk]);
  } else if (idx < 196608){               // w1T: [128][192]
    int j = idx - 172032; int col = j&127, k = j>>7;
    split_store(msg_w1[k*128+col], &w1T_h[col*192+k], &w1T_l[col*192+k]);
  } else if (idx < 212992){               // w2T: [128][128]
    int j = idx - 196608; int col = j&127, k = j>>7;
    split_store(msg_w2[k*128+col], &w2T_h[col*128+k], &w2T_l[col*128+k]);
  } else if (idx < 262144){               // awin: attn_w_in [384][128] as-is
    int j = idx - 212992;
    split_store(attn_w_in[j], &awin_h[j], &awin_l[j]);
  }
}

// ---------- counting sort of edges by destination ----------
__global__ void hist_kernel(const int* __restrict__ edge_index, int* __restrict__ counts){
  int e = blockIdx.x*blockDim.x + threadIdx.x;
  if (e < N_EDGES) atomicAdd(&counts[edge_index[N_EDGES + e]], 1);
}

__global__ void scan_kernel(const int* __restrict__ counts, int* __restrict__ offsets){
  __shared__ int buf[4096];
  int t = threadIdx.x; // 1024 threads
  for (int i=t;i<4096;i+=1024) buf[i]=counts[i];
  __syncthreads();
  for (int off=1; off<4096; off<<=1){
    int v[4];
    #pragma unroll
    for (int k=0;k<4;k++){ int i=t+k*1024; v[k] = (i>=off)?buf[i-off]:0; }
    __syncthreads();
    #pragma unroll
    for (int k=0;k<4;k++){ int i=t+k*1024; buf[i]+=v[k]; }
    __syncthreads();
  }
  for (int i=t;i<4096;i+=1024) offsets[i]=buf[i]-counts[i]; // exclusive
  if (t==0) offsets[4096]=buf[4095];
}

__global__ void scatter_kernel(const int* __restrict__ edge_index, const int* __restrict__ offsets,
                               int* __restrict__ cursor, int* __restrict__ edge_list){
  int e = blockIdx.x*blockDim.x + threadIdx.x;
  if (e < N_EDGES){
    int d = edge_index[N_EDGES + e];
    int pos = atomicAdd(&cursor[d], 1);
    edge_list[offsets[d] + pos] = e;
  }
}

// ---------- per-atom edge features: all-MFMA pipeline ----------
// phases: A rbf+sh (thread-per-(e,k), fully parallel)  B r1-GEMM (K=32 pad)
//         C r2-GEMM  D F-GEMM (F += r2^T @ sh, accumulated in C-regs)
__global__ __launch_bounds__(512) void edge_F_kernel(
  const float* __restrict__ edge_vectors, const float* __restrict__ edge_lengths,
  const float* __restrict__ rad_w1, const float* __restrict__ rad_b1,
  const unsigned short* __restrict__ w2t_h, const unsigned short* __restrict__ w2t_l,
  const float* __restrict__ rad_b2,
  const int* __restrict__ offsets, const int* __restrict__ edge_list,
  unsigned short* __restrict__ Fh, unsigned short* __restrict__ Fl)
{
  const int a = blockIdx.x, tid = threadIdx.x;
  const int w = tid >> 6, lane = tid & 63;
  const int l15 = lane & 15, lg = lane >> 4;
  const int wm = w >> 2, wn2 = w & 3;

  __shared__ unsigned short W2h[128][72], W2l[128][72];   // 36.9 KB
  __shared__ unsigned short W1h[64][36],  W1l[64][36];    // 9.2 KB (K padded 32)
  __shared__ unsigned short RBh[32][36],  RBl[32][36];    // 4.6 KB rbf (K pad 32)
  __shared__ unsigned short SHh[16][36],  SHl[16][36];    // 2.3 KB sh^T (j-major)
  __shared__ unsigned short R1h[32][72],  R1l[32][72];    // 9.2 KB
  __shared__ unsigned short R2h[128][36], R2l[128][36];   // 18.4 KB r2^T (c-major)

  // stage W2^T planes
  {
    const unsigned int* gh = (const unsigned int*)w2t_h;
    const unsigned int* gl = (const unsigned int*)w2t_l;
    for (int i = tid; i < 4096; i += 512){
      int c = i >> 5, kp = i & 31;
      *(unsigned int*)&W2h[c][kp*2] = gh[i];
      *(unsigned int*)&W2l[c][kp*2] = gl[i];
    }
  }
  // stage W1 c-major, K padded to 32 with zeros
  for (int i = tid; i < 2048; i += 512){
    int c = i >> 5, k = i & 31;
    float v = (k < 8) ? rad_w1[k*64 + c] : 0.f;
    split_store(v, &W1h[c][k], &W1l[c][k]);
  }
  // zero rbf (K-pad stays 0) and sh^T (rows 9..15 stay 0)
  for (int i = tid; i < 32*36; i += 512){ RBh[i/36][i%36]=0; RBl[i/36][i%36]=0; }
  for (int i = tid; i < 16*36; i += 512){ SHh[i/36][i%36]=0; SHl[i/36][i%36]=0; }

  const float b1v  = rad_b1[wn2*16 + l15];
  const float b2c0 = rad_b2[wn2*32 + l15];
  const float b2c1 = rad_b2[wn2*32 + 16 + l15];

  f32x4 facc = {0.f,0.f,0.f,0.f};

  const int beg = offsets[a], end = offsets[a+1];
  __syncthreads();

  for (int t0 = beg; t0 < end; t0 += 32){
    // ---- phase A: rbf (threads 0..255) + sh^T (threads 256..511) ----
    if (tid < 256){
      int e8 = tid >> 3, k = tid & 7;
      int ei = t0 + e8;
      int eid = edge_list[ei < end ? ei : beg];
      float d = edge_lengths[eid];
      float cut = 0.5f*(__cosf(d*PI6)+1.f)*(d<6.f?1.f:0.f);
      float rb = __sinf(d*((float)(k+1)*PI6))/d*cut;
      split_store(rb, &RBh[e8][k], &RBl[e8][k]);
    } else {
      int e8 = (tid-256) >> 3, u = tid & 7;
      int ei = t0 + e8;
      bool val = ei < end;
      int eid = edge_list[val ? ei : beg];
      float vx = edge_vectors[eid*3], vy = edge_vectors[eid*3+1], vz = edge_vectors[eid*3+2];
      float rn = sqrtf(vx*vx+vy*vy+vz*vz) + 1e-8f;
      float x = vx/rn, y = vy/rn, z = vz/rn;
      float sv;
      switch(u){
        case 0: sv = 1.f; break;
        case 1: sv = y; break;
        case 2: sv = z; break;
        case 3: sv = x; break;
        case 4: sv = 3.f*z*z-1.f; break;
        case 5: sv = x*z; break;
        case 6: sv = y*z; break;
        default: sv = x*y; break;
      }
      if (!val) sv = 0.f;
      split_store(sv, &SHh[u][e8], &SHl[u][e8]);
      if (u == 0){
        float s8 = val ? (x*x - y*y) : 0.f;
        split_store(s8, &SHh[8][e8], &SHl[8][e8]);
      }
    }
    __syncthreads();

    // ---- phase B: r1 = silu(rbf @ W1 + b1); 1 tile/wave ----
    {
      bf16x8 Ah = ld8(&RBh[wm*16 + l15][lg*8]);
      bf16x8 Al = ld8(&RBl[wm*16 + l15][lg*8]);
      bf16x8 Bh = ld8(&W1h[wn2*16 + l15][lg*8]);
      bf16x8 Bl = ld8(&W1l[wn2*16 + l15][lg*8]);
      f32x4 z = {0.f,0.f,0.f,0.f};
      z = MFMA(Ah,Bl,z); z = MFMA(Al,Bh,z); z = MFMA(Ah,Bh,z);
      #pragma unroll
      for (int r=0;r<4;r++){
        int e8 = wm*16 + lg*4 + r;
        int c  = wn2*16 + l15;
        float v = silu_f(z[r] + b1v);
        split_store(v, &R1h[e8][c], &R1l[e8][c]);
      }
    }
    __syncthreads();

    // ---- phase C: r2 = silu(r1 @ W2 + b2), stored transposed (c-major) ----
    {
      bf16x8 Ah0 = ld8(&R1h[wm*16+l15][lg*8]);
      bf16x8 Ah1 = ld8(&R1h[wm*16+l15][32+lg*8]);
      bf16x8 Al0 = ld8(&R1l[wm*16+l15][lg*8]);
      bf16x8 Al1 = ld8(&R1l[wm*16+l15][32+lg*8]);
      #pragma unroll
      for (int nt=0; nt<2; nt++){
        int c16 = wn2*2 + nt;
        bf16x8 Bh0 = ld8(&W2h[c16*16+l15][lg*8]);
        bf16x8 Bh1 = ld8(&W2h[c16*16+l15][32+lg*8]);
        bf16x8 Bl0 = ld8(&W2l[c16*16+l15][lg*8]);
        bf16x8 Bl1 = ld8(&W2l[c16*16+l15][32+lg*8]);
        f32x4 z = {0.f,0.f,0.f,0.f};
        z = MFMA(Al0,Bh0,z); z = MFMA(Al1,Bh1,z);
        z = MFMA(Ah0,Bl0,z); z = MFMA(Ah1,Bl1,z);
        z = MFMA(Ah0,Bh0,z); z = MFMA(Ah1,Bh1,z);
        float bb = nt ? b2c1 : b2c0;
        #pragma unroll
        for (int r=0;r<4;r++){
          int e8 = wm*16 + lg*4 + r;
          int c  = c16*16 + l15;
          float v = silu_f(z[r] + bb);
          split_store(v, &R2h[c][e8], &R2l[c][e8]);
        }
      }
    }
    __syncthreads();

    // ---- phase D: F += r2^T @ sh^T ; 1 c-tile/wave, C-reg accumulate ----
    {
      bf16x8 Ah = ld8(&R2h[w*16+l15][lg*8]);
      bf16x8 Al = ld8(&R2l[w*16+l15][lg*8]);
      bf16x8 Bh = ld8(&SHh[l15][lg*8]);
      bf16x8 Bl = ld8(&SHl[l15][lg*8]);
      facc = MFMA(Ah,Bl,facc);
      facc = MFMA(Al,Bh,facc);
      facc = MFMA(Ah,Bh,facc);
    }
    __syncthreads();
  }

  // write F planes: wave w owns c = w*16 + lg*4 + r ; col l15 = j (<9)
  if (l15 < 9){
    #pragma unroll
    for (int r=0;r<4;r++){
      int c = w*16 + lg*4 + r;
      size_t o = (size_t)l15*(N_ATOMS*128) + (size_t)a*128 + c;
      split_store(facc[r], &Fh[o], &Fl[o]);
    }
  }
}

// ---------- fused node: agg GEMM + msg MLP + qkv, all MFMA hi/lo ----------
__global__ __launch_bounds__(512) void node_kernel(
  const int* __restrict__ atomic_numbers, const float* __restrict__ atom_embed,
  const unsigned short* __restrict__ Fh, const unsigned short* __restrict__ Fl,
  const unsigned short* __restrict__ tpwT_h, const unsigned short* __restrict__ tpwT_l,
  const float* __restrict__ tp_b, const int* __restrict__ offsets,
  const unsigned short* __restrict__ w1T_h, const unsigned short* __restrict__ w1T_l,
  const float* __restrict__ msg_b1,
  const unsigned short* __restrict__ w2T_h, const unsigned short* __restrict__ w2T_l,
  const float* __restrict__ msg_b2,
  const unsigned short* __restrict__ awin_h, const unsigned short* __restrict__ awin_l,
  const float* __restrict__ attn_b_in,
  float* __restrict__ upd_out, float* __restrict__ qkv_out)
{
  const int a0 = blockIdx.x*16, tid = threadIdx.x;
  const int w = tid>>6, lane = tid&63, l15 = lane&15, lg = lane>>4;

  __shared__ unsigned short Ch[16][200], Cl[16][200];   // comb (192 + pad)
  __shared__ unsigned short Hh[16][136], Hl[16][136];   // hid
  __shared__ unsigned short Uh[16][136], Ul[16][136];   // upd

  for (int i=tid; i<1024; i+=512){
    int a16=i>>6, k=i&63;
    float v = atom_embed[atomic_numbers[a0+a16]*64+k];
    split_store(v, &Ch[a16][k], &Cl[a16][k]);
  }

  // agg GEMM
  {
    f32x4 z = {0.f,0.f,0.f,0.f};
    for (int ch=0; ch<36; ch++){
      int k0=ch*32, j=k0>>7, c0=k0&127;
      size_t aoff = (size_t)j*(N_ATOMS*128) + (size_t)(a0+l15)*128 + c0 + lg*8;
      bf16x8 Ah=ld8(Fh+aoff), Al=ld8(Fl+aoff);
      size_t boff = (size_t)(w*16+l15)*1152 + k0 + lg*8;
      bf16x8 Bh=ld8(tpwT_h+boff), Bl=ld8(tpwT_l+boff);
      z = MFMA(Ah,Bl,z); z = MFMA(Al,Bh,z); z = MFMA(Ah,Bh,z);
    }
    int col = w*16+l15;
    float tb = tp_b[col];
    #pragma unroll
    for (int r=0;r<4;r++){
      int row = lg*4+r, arow = a0+row;
      float deg = (float)(offsets[arow+1]-offsets[arow]);
      float v = z[r] + tb*deg;
      split_store(v, &Ch[row][64+col], &Cl[row][64+col]);
    }
  }
  __syncthreads();

  // msg1
  {
    f32x4 z = {0.f,0.f,0.f,0.f};
    #pragma unroll
    for (int ch=0; ch<6; ch++){
      int k0=ch*32;
      bf16x8 Ah=ld8(&Ch[l15][k0+lg*8]), Al=ld8(&Cl[l15][k0+lg*8]);
      size_t boff=(size_t)(w*16+l15)*192 + k0 + lg*8;
      bf16x8 Bh=ld8(w1T_h+boff), Bl=ld8(w1T_l+boff);
      z = MFMA(Ah,Bl,z); z = MFMA(Al,Bh,z); z = MFMA(Ah,Bh,z);
    }
    int col = w*16+l15;
    float mb = msg_b1[col];
    #pragma unroll
    for (int r=0;r<4;r++){
      int row = lg*4+r;
      float v = silu_f(z[r]+mb);
      split_store(v, &Hh[row][col], &Hl[row][col]);
    }
  }
  __syncthreads();

  // msg2
  {
    f32x4 z = {0.f,0.f,0.f,0.f};
    #pragma unroll
    for (int ch=0; ch<4; ch++){
      int k0=ch*32;
      bf16x8 Ah=ld8(&Hh[l15][k0+lg*8]), Al=ld8(&Hl[l15][k0+lg*8]);
      size_t boff=(size_t)(w*16+l15)*128 + k0 + lg*8;
      bf16x8 Bh=ld8(w2T_h+boff), Bl=ld8(w2T_l+boff);
      z = MFMA(Ah,Bl,z); z = MFMA(Al,Bh,z); z = MFMA(Ah,Bh,z);
    }
    int col = w*16+l15;
    float mb = msg_b2[col];
    #pragma unroll
    for (int r=0;r<4;r++){
      int row = lg*4+r;
      float v = z[r]+mb;
      upd_out[(size_t)(a0+row)*128 + col] = v;
      split_store(v, &Uh[row][col], &Ul[row][col]);
    }
  }
  __syncthreads();

  // qkv
  #pragma unroll
  for (int t3=0; t3<3; t3++){
    f32x4 z = {0.f,0.f,0.f,0.f};
    int col = (w*3+t3)*16 + l15;
    #pragma unroll
    for (int ch=0; ch<4; ch++){
      int k0=ch*32;
      bf16x8 Ah=ld8(&Uh[l15][k0+lg*8]), Al=ld8(&Ul[l15][k0+lg*8]);
      size_t boff=(size_t)col*128 + k0 + lg*8;
      bf16x8 Bh=ld8(awin_h+boff), Bl=ld8(awin_l+boff);
      z = MFMA(Ah,Bl,z); z = MFMA(Al,Bh,z); z = MFMA(Ah,Bh,z);
    }
    float ab = attn_b_in[col];
    #pragma unroll
    for (int r=0;r<4;r++){
      int row = lg*4+r;
      qkv_out[(size_t)(a0+row)*384 + col] = z[r]+ab;
    }
  }
}

// ---------- MFMA flash attention: 4 heads, N=4096, D=32, bf16 matmuls ----------
__global__ __launch_bounds__(256) void attn_kernel(const float* __restrict__ qkv, float* __restrict__ att){
  const int b = blockIdx.x;
  const int h = b >> 7, qt = b & 127;
  const int tid = threadIdx.x;
  const int w = tid >> 6, lane = tid & 63;
  const int wq = w & 1, wk = w >> 1;
  const int l15 = lane & 15, lg = lane >> 4;
  const int n0 = qt*32;

  __shared__ unsigned short Qs[32][36];
  __shared__ unsigned short Ks[2][2][64][36];
  __shared__ unsigned short Vt[2][2][32][66];
  __shared__ unsigned short Ps[8][16][68];
  __shared__ float MB[2][64][16];

  const float scale = 0.17677669529663687f;

  {
    int qr = tid>>3, d4 = (tid&7)*4;
    const float4 qf = *(const float4*)(qkv + (size_t)(n0+qr)*384 + h*32 + d4);
    unsigned int* dst = (unsigned int*)&Qs[qr][d4];
    dst[0] = f2bf(qf.x*scale) | (f2bf(qf.y*scale)<<16);
    dst[1] = f2bf(qf.z*scale) | (f2bf(qf.w*scale)<<16);
  }

  const int hf = tid >> 7, u = tid & 127;
  const int skey = u >> 1, sd16 = (u & 1)*16;
  float4 kA,kB,kC,kD, vA,vB,vC,vD;

  #define LOADG(T) { \
    const float* kp = qkv + (size_t)(((hf*32+(T))*64 + skey))*384 + 128 + h*32 + sd16; \
    kA = *(const float4*)kp;        kB = *(const float4*)(kp+4); \
    kC = *(const float4*)(kp+8);    kD = *(const float4*)(kp+12); \
    const float* vp = kp + 128; \
    vA = *(const float4*)vp;        vB = *(const float4*)(vp+4); \
    vC = *(const float4*)(vp+8);    vD = *(const float4*)(vp+12); }

  #define WRITEL(BUF) { \
    unsigned int* kdst = (unsigned int*)&Ks[BUF][hf][skey][sd16]; \
    kdst[0]=f2bf(kA.x)|(f2bf(kA.y)<<16); kdst[1]=f2bf(kA.z)|(f2bf(kA.w)<<16); \
    kdst[2]=f2bf(kB.x)|(f2bf(kB.y)<<16); kdst[3]=f2bf(kB.z)|(f2bf(kB.w)<<16); \
    kdst[4]=f2bf(kC.x)|(f2bf(kC.y)<<16); kdst[5]=f2bf(kC.z)|(f2bf(kC.w)<<16); \
    kdst[6]=f2bf(kD.x)|(f2bf(kD.y)<<16); kdst[7]=f2bf(kD.z)|(f2bf(kD.w)<<16); \
    Vt[BUF][hf][sd16+ 0][skey]=(unsigned short)f2bf(vA.x); \
    Vt[BUF][hf][sd16+ 1][skey]=(unsigned short)f2bf(vA.y); \
    Vt[BUF][hf][sd16+ 2][skey]=(unsigned short)f2bf(vA.z); \
    Vt[BUF][hf][sd16+ 3][skey]=(unsigned short)f2bf(vA.w); \
    Vt[BUF][hf][sd16+ 4][skey]=(unsigned short)f2bf(vB.x); \
    Vt[BUF][hf][sd16+ 5][skey]=(unsigned short)f2bf(vB.y); \
    Vt[BUF][hf][sd16+ 6][skey]=(unsigned short)f2bf(vB.z); \
    Vt[BUF][hf][sd16+ 7][skey]=(unsigned short)f2bf(vB.w); \
    Vt[BUF][hf][sd16+ 8][skey]=(unsigned short)f2bf(vC.x); \
    Vt[BUF][hf][sd16+ 9][skey]=(unsigned short)f2bf(vC.y); \
    Vt[BUF][hf][sd16+10][skey]=(unsigned short)f2bf(vC.z); \
    Vt[BUF][hf][sd16+11][skey]=(unsigned short)f2bf(vC.w); \
    Vt[BUF][hf][sd16+12][skey]=(unsigned short)f2bf(vD.x); \
    Vt[BUF][hf][sd16+13][skey]=(unsigned short)f2bf(vD.y); \
    Vt[BUF][hf][sd16+14][skey]=(unsigned short)f2bf(vD.z); \
    Vt[BUF][hf][sd16+15][skey]=(unsigned short)f2bf(vD.w); }

  LOADG(0);
  WRITEL(0);
  __syncthreads();

  bf16x8 aQ = ld8(&Qs[wq*16 + l15][lg*8]);

  float m[4] = {-3e38f,-3e38f,-3e38f,-3e38f};
  float su[4] = {0.f,0.f,0.f,0.f};
  f32x4 oacc[2] = {{0.f,0.f,0.f,0.f},{0.f,0.f,0.f,0.f}};

  for (int t=0; t<32; t++){
    const int cur = t&1;
    if (t<31) LOADG(t+1);

    f32x4 s[4];
    #pragma unroll
    for (int n=0;n<4;n++){
      bf16x8 bK = ld8(&Ks[cur][wk][n*16+l15][lg*8]);
      f32x4 z = {0.f,0.f,0.f,0.f};
      s[n] = MFMA(aQ, bK, z);
    }

    float csc[4], psum[4];
    #pragma unroll
    for (int r=0;r<4;r++){
      float mloc = fmaxf(fmaxf(s[0][r], s[1][r]), fmaxf(s[2][r], s[3][r]));
      #pragma unroll
      for (int off=1; off<16; off<<=1) mloc = fmaxf(mloc, __shfl_xor(mloc, off, 64));
      float mn = fmaxf(m[r], mloc);
      csc[r] = __expf(m[r] - mn);
      m[r] = mn;
      psum[r] = 0.f;
    }
    #pragma unroll
    for (int n=0;n<4;n++){
      #pragma unroll
      for (int r=0;r<4;r++){
        float p = __expf(s[n][r] - m[r]);
        psum[r] += p;
        Ps[w][lg*4+r][n*16+l15] = (unsigned short)f2bf(p);
      }
    }
    #pragma unroll
    for (int r=0;r<4;r++){
      #pragma unroll
      for (int off=1; off<16; off<<=1) psum[r] += __shfl_xor(psum[r], off, 64);
      su[r] = su[r]*csc[r] + psum[r];
    }
    #pragma unroll
    for (int nd=0;nd<2;nd++){
      #pragma unroll
      for (int r=0;r<4;r++) oacc[nd][r] *= csc[r];
    }

    #pragma unroll
    for (int c=0;c<2;c++){
      bf16x8 aP = ld8(&Ps[w][l15][c*32 + lg*8]);
      #pragma unroll
      for (int nd=0;nd<2;nd++){
        bf16x8 bV = ld8(&Vt[cur][wk][nd*16+l15][c*32 + lg*8]);
        oacc[nd] = MFMA(aP, bV, oacc[nd]);
      }
    }

    __syncthreads();
    if (t<31) WRITEL((t+1)&1);
    __syncthreads();
  }

  if (wk==1){
    #pragma unroll
    for (int r=0;r<4;r++){ MB[wq][lane][r] = m[r]; MB[wq][lane][4+r] = su[r]; }
    #pragma unroll
    for (int nd=0;nd<2;nd++)
      #pragma unroll
      for (int r=0;r<4;r++) MB[wq][lane][8+nd*4+r] = oacc[nd][r];
  }
  __syncthreads();
  if (wk==0){
    #pragma unroll
    for (int r=0;r<4;r++){
      float m1 = MB[wq][lane][r], s1 = MB[wq][lane][4+r];
      float mf = fmaxf(m[r], m1);
      float c0 = __expf(m[r]-mf), c1 = __expf(m1-mf);
      float stot = su[r]*c0 + s1*c1;
      float inv = 1.f/stot;
      #pragma unroll
      for (int nd=0;nd<2;nd++){
        float o = oacc[nd][r]*c0 + MB[wq][lane][8+nd*4+r]*c1;
        att[(size_t)(n0 + wq*16 + lg*4 + r)*128 + h*32 + nd*16 + l15] = o*inv;
      }
    }
  }
  #undef LOADG
  #undef WRITEL
}

// ---------- epilogue: 8 atoms, 512 threads, LDS-staged operands ----------
__global__ __launch_bounds__(512) void final_kernel(
  const float* __restrict__ att, const float* __restrict__ upd,
  const float* __restrict__ wt_out, const float* __restrict__ attn_b_out,
  const float* __restrict__ gate_w, const float* __restrict__ gate_b,
  const float* __restrict__ out_w, const float* __restrict__ out_b,
  float* __restrict__ out)
{
  const int a0 = blockIdx.x*8, tid = threadIdx.x;
  const int g = tid >> 7, o = tid & 127;
  __shared__ float att_s[8][128], upd_s[8][128], tmps[8][128];
  for (int i=tid; i<1024; i+=512){
    int a8 = i>>7, k = i&127;
    att_s[a8][k] = att[(a0+a8)*128+k];
    upd_s[a8][k] = upd[(a0+a8)*128+k];
  }
  __syncthreads();
  const int aA = 2*g, aB = 2*g+1;
  float a2A = attn_b_out[o], a2B = a2A;
  float gA = gate_b[o], gB = gA;
  for (int k=0;k<128;k++){
    float wa = wt_out[k*128+o];
    float wg = gate_w[k*128+o];
    a2A += att_s[aA][k]*wa; a2B += att_s[aB][k]*wa;
    gA  += upd_s[aA][k]*wg; gB  += upd_s[aB][k]*wg;
  }
  gA = sigmoid_f(gA); gB = sigmoid_f(gB);
  tmps[aA][o] = gA*a2A + (1.f-gA)*upd_s[aA][o];
  tmps[aB][o] = gB*a2B + (1.f-gB)*upd_s[aB][o];
  __syncthreads();
  float ouA = out_b[o], ouB = ouA;
  for (int k=0;k<128;k++){
    float w = out_w[k*128+o];
    ouA += tmps[aA][k]*w; ouB += tmps[aB][k]*w;
  }
  out[(a0+aA)*128+o] = ouA;
  out[(a0+aB)*128+o] = ouB;
}

extern "C" void kernel_launch(void* const* d_in, const int* in_sizes, int n_in,
                              void* d_out, int out_size, void* d_ws, size_t ws_size,
                              hipStream_t stream){
  const int*   atomic_numbers = (const int*)  d_in[0];
  const int*   edge_index     = (const int*)  d_in[2];
  const float* edge_vectors   = (const float*)d_in[3];
  const float* edge_lengths   = (const float*)d_in[4];
  const float* atom_embed     = (const float*)d_in[5];
  const float* rad_w1 = (const float*)d_in[6];
  const float* rad_b1 = (const float*)d_in[7];
  const float* rad_w2 = (const float*)d_in[8];
  const float* rad_b2 = (const float*)d_in[9];
  const float* tp_w   = (const float*)d_in[10];
  const float* tp_b   = (const float*)d_in[11];
  const float* msg_w1 = (const float*)d_in[12];
  const float* msg_b1 = (const float*)d_in[13];
  const float* msg_w2 = (const float*)d_in[14];
  const float* msg_b2 = (const float*)d_in[15];
  const float* attn_w_in  = (const float*)d_in[16];
  const float* attn_b_in  = (const float*)d_in[17];
  const float* attn_w_out = (const float*)d_in[18];
  const float* attn_b_out = (const float*)d_in[19];
  const float* gate_w = (const float*)d_in[20];
  const float* gate_b = (const float*)d_in[21];
  const float* out_w  = (const float*)d_in[22];
  const float* out_b  = (const float*)d_in[23];

  // workspace layout (bytes)
  char* ws = (char*)d_ws;
  int* counts    = (int*)(ws);                       // [0,16384)
  int* cursor    = (int*)(ws + 16384);               // [16384,32768)
  int* offsets   = (int*)(ws + 32768);               // [32768,49156)
  int* edge_list = (int*)(ws + 53248);               // [53248,577536)
  float* wt_out  = (float*)(ws + 577536);            // [577536,643072)
  unsigned short* w2t_h  = (unsigned short*)(ws + 643072);   // 16 KB
  unsigned short* w2t_l  = (unsigned short*)(ws + 659456);   // 16 KB
  unsigned short* tpwT_h = (unsigned short*)(ws + 675840);   // 288 KB
  unsigned short* tpwT_l = (unsigned short*)(ws + 970752);   // 288 KB
  unsigned short* w1T_h  = (unsigned short*)(ws + 1265664);  // 48 KB
  unsigned short* w1T_l  = (unsigned short*)(ws + 1314816);  // 48 KB
  unsigned short* w2T_h  = (unsigned short*)(ws + 1363968);  // 32 KB
  unsigned short* w2T_l  = (unsigned short*)(ws + 1396736);  // 32 KB
  unsigned short* awin_h = (unsigned short*)(ws + 1429504);  // 96 KB
  unsigned short* awin_l = (unsigned short*)(ws + 1527808);  // 96 KB
  unsigned short* Fbf_h  = (unsigned short*)(ws + 1626112);  // 9.44 MB
  unsigned short* Fbf_l  = (unsigned short*)(ws + 11063296); // 9.44 MB
  float* att     = (float*)(ws + 1626112);           // aliases Fbf_h (dead after node)
  float* upd     = (float*)(ws + 20500480);          // 2 MB
  float* qkv     = (float*)(ws + 22597632);          // 6.3 MB (end 28889088)

  prep_kernel<<<1024, 256, 0, stream>>>(attn_w_out, rad_w2, tp_w, msg_w1, msg_w2, attn_w_in,
      wt_out, w2t_h, w2t_l, tpwT_h, tpwT_l, w1T_h, w1T_l, w2T_h, w2T_l, awin_h, awin_l);
  hipMemsetAsync(ws, 0, 32768, stream);  // counts + cursor
  hist_kernel<<<(N_EDGES+255)/256, 256, 0, stream>>>(edge_index, counts);
  scan_kernel<<<1, 1024, 0, stream>>>(counts, offsets);
  scatter_kernel<<<(N_EDGES+255)/256, 256, 0, stream>>>(edge_index, offsets, cursor, edge_list);
  edge_F_kernel<<<N_ATOMS, 512, 0, stream>>>(edge_vectors, edge_lengths,
      rad_w1, rad_b1, w2t_h, w2t_l, rad_b2, offsets, edge_list, Fbf_h, Fbf_l);
  node_kernel<<<N_ATOMS/16, 512, 0, stream>>>(atomic_numbers, atom_embed,
      Fbf_h, Fbf_l, tpwT_h, tpwT_l, tp_b, offsets,
      w1T_h, w1T_l, msg_b1, w2T_h, w2T_l, msg_b2, awin_h, awin_l, attn_b_in,
      upd, qkv);
  attn_kernel<<<512, 256, 0, stream>>>(qkv, att);
  final_kernel<<<N_ATOMS/8, 512, 0, stream>>>(att, upd, wt_out, attn_b_out,
      gate_w, gate_b, out_w, out_b, (float*)d_out);
}

// Round 13
// 215.271 us; speedup vs baseline: 2.0732x; 1.1479x over previous
//
#include <hip/hip_runtime.h>
#include <math.h>

#define N_ATOMS 4096
#define N_EDGES 131072
#define PI6 0.52359877559829887f

typedef __attribute__((ext_vector_type(8))) short bf16x8;
typedef __attribute__((ext_vector_type(4))) float f32x4;

#define MFMA(A,B,C) __builtin_amdgcn_mfma_f32_16x16x32_bf16((A),(B),(C),0,0,0)

__device__ __forceinline__ float silu_f(float x){ return x / (1.f + __expf(-x)); }
__device__ __forceinline__ float sigmoid_f(float x){ return 1.f / (1.f + __expf(-x)); }
__device__ __forceinline__ unsigned int f2bf(float f){
  unsigned int u = __float_as_uint(f);
  return (u + 0x7FFFu + ((u>>16)&1u)) >> 16;
}
__device__ __forceinline__ bf16x8 ld8(const unsigned short* p){
  union { unsigned int u[4]; bf16x8 v; } r;
  const unsigned int* q = (const unsigned int*)p;
  r.u[0]=q[0]; r.u[1]=q[1]; r.u[2]=q[2]; r.u[3]=q[3];
  return r.v;
}
__device__ __forceinline__ void split_store(float v, unsigned short* ph, unsigned short* pl){
  unsigned int hb = f2bf(v);
  *ph = (unsigned short)hb;
  *pl = (unsigned short)f2bf(v - __uint_as_float(hb<<16));
}

// ---------- prep: wt_out transpose (fp32) + all bf16 hi/lo weight planes ----------
__global__ __launch_bounds__(256) void prep_kernel(
  const float* __restrict__ attn_w_out, const float* __restrict__ rad_w2,
  const float* __restrict__ tp_w, const float* __restrict__ msg_w1,
  const float* __restrict__ msg_w2, const float* __restrict__ attn_w_in,
  float* __restrict__ wt_out,
  unsigned short* __restrict__ w2t_h, unsigned short* __restrict__ w2t_l,
  unsigned short* __restrict__ tpwT_h, unsigned short* __restrict__ tpwT_l,
  unsigned short* __restrict__ w1T_h, unsigned short* __restrict__ w1T_l,
  unsigned short* __restrict__ w2T_h, unsigned short* __restrict__ w2T_l,
  unsigned short* __restrict__ awin_h, unsigned short* __restrict__ awin_l)
{
  int idx = blockIdx.x*256 + threadIdx.x;
  if (idx < 16384){                       // wt_out: [128][128] transpose fp32
    int i = idx>>7, k = idx&127;
    wt_out[k*128+i] = attn_w_out[idx];
  } else if (idx < 24576){                // w2t: rad_w2^T hi/lo [128][64]
    int j = idx - 16384; int k = j>>7, c = j&127;
    split_store(rad_w2[k*128+c], &w2t_h[c*64+k], &w2t_l[c*64+k]);
  } else if (idx < 172032){               // tpwT: [128 col][1152 k] reordered
    int j = idx - 24576; int col = j&127, kk = j>>7;
    int jj = kk>>7, c = kk&127;
    int r = (jj==0)? c : (jj<4 ? 128 + c*3 + (jj-1) : 512 + c*5 + (jj-4));
    split_store(tp_w[r*128+col], &tpwT_h[col*1152+kk], &tpwT_l[col*1152+kk]);
  } else if (idx < 196608){               // w1T: [128][192]
    int j = idx - 172032; int col = j&127, k = j>>7;
    split_store(msg_w1[k*128+col], &w1T_h[col*192+k], &w1T_l[col*192+k]);
  } else if (idx < 212992){               // w2T: [128][128]
    int j = idx - 196608; int col = j&127, k = j>>7;
    split_store(msg_w2[k*128+col], &w2T_h[col*128+k], &w2T_l[col*128+k]);
  } else if (idx < 262144){               // awin: attn_w_in [384][128] as-is
    int j = idx - 212992;
    split_store(attn_w_in[j], &awin_h[j], &awin_l[j]);
  }
}

// ---------- counting sort of edges by destination ----------
__global__ void hist_kernel(const int* __restrict__ edge_index, int* __restrict__ counts){
  int e = blockIdx.x*blockDim.x + threadIdx.x;
  if (e < N_EDGES) atomicAdd(&counts[edge_index[N_EDGES + e]], 1);
}

__global__ void scan_kernel(const int* __restrict__ counts, int* __restrict__ offsets){
  __shared__ int buf[4096];
  int t = threadIdx.x; // 1024 threads
  for (int i=t;i<4096;i+=1024) buf[i]=counts[i];
  __syncthreads();
  for (int off=1; off<4096; off<<=1){
    int v[4];
    #pragma unroll
    for (int k=0;k<4;k++){ int i=t+k*1024; v[k] = (i>=off)?buf[i-off]:0; }
    __syncthreads();
    #pragma unroll
    for (int k=0;k<4;k++){ int i=t+k*1024; buf[i]+=v[k]; }
    __syncthreads();
  }
  for (int i=t;i<4096;i+=1024) offsets[i]=buf[i]-counts[i]; // exclusive
  if (t==0) offsets[4096]=buf[4095];
}

__global__ void scatter_kernel(const int* __restrict__ edge_index, const int* __restrict__ offsets,
                               int* __restrict__ cursor, int* __restrict__ edge_list){
  int e = blockIdx.x*blockDim.x + threadIdx.x;
  if (e < N_EDGES){
    int d = edge_index[N_EDGES + e];
    int pos = atomicAdd(&cursor[d], 1);
    edge_list[offsets[d] + pos] = e;
  }
}

// ---------- per-atom edge features: all-MFMA pipeline ----------
__global__ __launch_bounds__(512) void edge_F_kernel(
  const float* __restrict__ edge_vectors, const float* __restrict__ edge_lengths,
  const float* __restrict__ rad_w1, const float* __restrict__ rad_b1,
  const unsigned short* __restrict__ w2t_h, const unsigned short* __restrict__ w2t_l,
  const float* __restrict__ rad_b2,
  const int* __restrict__ offsets, const int* __restrict__ edge_list,
  unsigned short* __restrict__ Fh, unsigned short* __restrict__ Fl)
{
  const int a = blockIdx.x, tid = threadIdx.x;
  const int w = tid >> 6, lane = tid & 63;
  const int l15 = lane & 15, lg = lane >> 4;
  const int wm = w >> 2, wn2 = w & 3;

  __shared__ unsigned short W2h[128][72], W2l[128][72];
  __shared__ unsigned short W1h[64][36],  W1l[64][36];
  __shared__ unsigned short RBh[32][36],  RBl[32][36];
  __shared__ unsigned short SHh[16][36],  SHl[16][36];
  __shared__ unsigned short R1h[32][72],  R1l[32][72];
  __shared__ unsigned short R2h[128][36], R2l[128][36];

  {
    const unsigned int* gh = (const unsigned int*)w2t_h;
    const unsigned int* gl = (const unsigned int*)w2t_l;
    for (int i = tid; i < 4096; i += 512){
      int c = i >> 5, kp = i & 31;
      *(unsigned int*)&W2h[c][kp*2] = gh[i];
      *(unsigned int*)&W2l[c][kp*2] = gl[i];
    }
  }
  for (int i = tid; i < 2048; i += 512){
    int c = i >> 5, k = i & 31;
    float v = (k < 8) ? rad_w1[k*64 + c] : 0.f;
    split_store(v, &W1h[c][k], &W1l[c][k]);
  }
  for (int i = tid; i < 32*36; i += 512){ RBh[i/36][i%36]=0; RBl[i/36][i%36]=0; }
  for (int i = tid; i < 16*36; i += 512){ SHh[i/36][i%36]=0; SHl[i/36][i%36]=0; }

  const float b1v  = rad_b1[wn2*16 + l15];
  const float b2c0 = rad_b2[wn2*32 + l15];
  const float b2c1 = rad_b2[wn2*32 + 16 + l15];

  f32x4 facc = {0.f,0.f,0.f,0.f};

  const int beg = offsets[a], end = offsets[a+1];
  __syncthreads();

  for (int t0 = beg; t0 < end; t0 += 32){
    if (tid < 256){
      int e8 = tid >> 3, k = tid & 7;
      int ei = t0 + e8;
      int eid = edge_list[ei < end ? ei : beg];
      float d = edge_lengths[eid];
      float cut = 0.5f*(__cosf(d*PI6)+1.f)*(d<6.f?1.f:0.f);
      float rb = __sinf(d*((float)(k+1)*PI6))/d*cut;
      split_store(rb, &RBh[e8][k], &RBl[e8][k]);
    } else {
      int e8 = (tid-256) >> 3, u = tid & 7;
      int ei = t0 + e8;
      bool val = ei < end;
      int eid = edge_list[val ? ei : beg];
      float vx = edge_vectors[eid*3], vy = edge_vectors[eid*3+1], vz = edge_vectors[eid*3+2];
      float rn = sqrtf(vx*vx+vy*vy+vz*vz) + 1e-8f;
      float x = vx/rn, y = vy/rn, z = vz/rn;
      float sv;
      switch(u){
        case 0: sv = 1.f; break;
        case 1: sv = y; break;
        case 2: sv = z; break;
        case 3: sv = x; break;
        case 4: sv = 3.f*z*z-1.f; break;
        case 5: sv = x*z; break;
        case 6: sv = y*z; break;
        default: sv = x*y; break;
      }
      if (!val) sv = 0.f;
      split_store(sv, &SHh[u][e8], &SHl[u][e8]);
      if (u == 0){
        float s8 = val ? (x*x - y*y) : 0.f;
        split_store(s8, &SHh[8][e8], &SHl[8][e8]);
      }
    }
    __syncthreads();

    {
      bf16x8 Ah = ld8(&RBh[wm*16 + l15][lg*8]);
      bf16x8 Al = ld8(&RBl[wm*16 + l15][lg*8]);
      bf16x8 Bh = ld8(&W1h[wn2*16 + l15][lg*8]);
      bf16x8 Bl = ld8(&W1l[wn2*16 + l15][lg*8]);
      f32x4 z = {0.f,0.f,0.f,0.f};
      z = MFMA(Ah,Bl,z); z = MFMA(Al,Bh,z); z = MFMA(Ah,Bh,z);
      #pragma unroll
      for (int r=0;r<4;r++){
        int e8 = wm*16 + lg*4 + r;
        int c  = wn2*16 + l15;
        float v = silu_f(z[r] + b1v);
        split_store(v, &R1h[e8][c], &R1l[e8][c]);
      }
    }
    __syncthreads();

    {
      bf16x8 Ah0 = ld8(&R1h[wm*16+l15][lg*8]);
      bf16x8 Ah1 = ld8(&R1h[wm*16+l15][32+lg*8]);
      bf16x8 Al0 = ld8(&R1l[wm*16+l15][lg*8]);
      bf16x8 Al1 = ld8(&R1l[wm*16+l15][32+lg*8]);
      #pragma unroll
      for (int nt=0; nt<2; nt++){
        int c16 = wn2*2 + nt;
        bf16x8 Bh0 = ld8(&W2h[c16*16+l15][lg*8]);
        bf16x8 Bh1 = ld8(&W2h[c16*16+l15][32+lg*8]);
        bf16x8 Bl0 = ld8(&W2l[c16*16+l15][lg*8]);
        bf16x8 Bl1 = ld8(&W2l[c16*16+l15][32+lg*8]);
        f32x4 z = {0.f,0.f,0.f,0.f};
        z = MFMA(Al0,Bh0,z); z = MFMA(Al1,Bh1,z);
        z = MFMA(Ah0,Bl0,z); z = MFMA(Ah1,Bl1,z);
        z = MFMA(Ah0,Bh0,z); z = MFMA(Ah1,Bh1,z);
        float bb = nt ? b2c1 : b2c0;
        #pragma unroll
        for (int r=0;r<4;r++){
          int e8 = wm*16 + lg*4 + r;
          int c  = c16*16 + l15;
          float v = silu_f(z[r] + bb);
          split_store(v, &R2h[c][e8], &R2l[c][e8]);
        }
      }
    }
    __syncthreads();

    {
      bf16x8 Ah = ld8(&R2h[w*16+l15][lg*8]);
      bf16x8 Al = ld8(&R2l[w*16+l15][lg*8]);
      bf16x8 Bh = ld8(&SHh[l15][lg*8]);
      bf16x8 Bl = ld8(&SHl[l15][lg*8]);
      facc = MFMA(Ah,Bl,facc);
      facc = MFMA(Al,Bh,facc);
      facc = MFMA(Ah,Bh,facc);
    }
    __syncthreads();
  }

  if (l15 < 9){
    #pragma unroll
    for (int r=0;r<4;r++){
      int c = w*16 + lg*4 + r;
      size_t o = (size_t)l15*(N_ATOMS*128) + (size_t)a*128 + c;
      split_store(facc[r], &Fh[o], &Fl[o]);
    }
  }
}

// ---------- fused node: agg GEMM + msg MLP + qkv (bf16 Q/K/V^T out) ----------
__global__ __launch_bounds__(512) void node_kernel(
  const int* __restrict__ atomic_numbers, const float* __restrict__ atom_embed,
  const unsigned short* __restrict__ Fh, const unsigned short* __restrict__ Fl,
  const unsigned short* __restrict__ tpwT_h, const unsigned short* __restrict__ tpwT_l,
  const float* __restrict__ tp_b, const int* __restrict__ offsets,
  const unsigned short* __restrict__ w1T_h, const unsigned short* __restrict__ w1T_l,
  const float* __restrict__ msg_b1,
  const unsigned short* __restrict__ w2T_h, const unsigned short* __restrict__ w2T_l,
  const float* __restrict__ msg_b2,
  const unsigned short* __restrict__ awin_h, const unsigned short* __restrict__ awin_l,
  const float* __restrict__ attn_b_in,
  float* __restrict__ upd_out,
  unsigned short* __restrict__ Qbf, unsigned short* __restrict__ Kbf,
  unsigned short* __restrict__ Vtb)
{
  const int a0 = blockIdx.x*16, tid = threadIdx.x;
  const int w = tid>>6, lane = tid&63, l15 = lane&15, lg = lane>>4;

  __shared__ unsigned short Ch[16][200], Cl[16][200];
  __shared__ unsigned short Hh[16][136], Hl[16][136];
  __shared__ unsigned short Uh[16][136], Ul[16][136];

  for (int i=tid; i<1024; i+=512){
    int a16=i>>6, k=i&63;
    float v = atom_embed[atomic_numbers[a0+a16]*64+k];
    split_store(v, &Ch[a16][k], &Cl[a16][k]);
  }

  // agg GEMM
  {
    f32x4 z = {0.f,0.f,0.f,0.f};
    for (int ch=0; ch<36; ch++){
      int k0=ch*32, j=k0>>7, c0=k0&127;
      size_t aoff = (size_t)j*(N_ATOMS*128) + (size_t)(a0+l15)*128 + c0 + lg*8;
      bf16x8 Ah=ld8(Fh+aoff), Al=ld8(Fl+aoff);
      size_t boff = (size_t)(w*16+l15)*1152 + k0 + lg*8;
      bf16x8 Bh=ld8(tpwT_h+boff), Bl=ld8(tpwT_l+boff);
      z = MFMA(Ah,Bl,z); z = MFMA(Al,Bh,z); z = MFMA(Ah,Bh,z);
    }
    int col = w*16+l15;
    float tb = tp_b[col];
    #pragma unroll
    for (int r=0;r<4;r++){
      int row = lg*4+r, arow = a0+row;
      float deg = (float)(offsets[arow+1]-offsets[arow]);
      float v = z[r] + tb*deg;
      split_store(v, &Ch[row][64+col], &Cl[row][64+col]);
    }
  }
  __syncthreads();

  // msg1
  {
    f32x4 z = {0.f,0.f,0.f,0.f};
    #pragma unroll
    for (int ch=0; ch<6; ch++){
      int k0=ch*32;
      bf16x8 Ah=ld8(&Ch[l15][k0+lg*8]), Al=ld8(&Cl[l15][k0+lg*8]);
      size_t boff=(size_t)(w*16+l15)*192 + k0 + lg*8;
      bf16x8 Bh=ld8(w1T_h+boff), Bl=ld8(w1T_l+boff);
      z = MFMA(Ah,Bl,z); z = MFMA(Al,Bh,z); z = MFMA(Ah,Bh,z);
    }
    int col = w*16+l15;
    float mb = msg_b1[col];
    #pragma unroll
    for (int r=0;r<4;r++){
      int row = lg*4+r;
      float v = silu_f(z[r]+mb);
      split_store(v, &Hh[row][col], &Hl[row][col]);
    }
  }
  __syncthreads();

  // msg2
  {
    f32x4 z = {0.f,0.f,0.f,0.f};
    #pragma unroll
    for (int ch=0; ch<4; ch++){
      int k0=ch*32;
      bf16x8 Ah=ld8(&Hh[l15][k0+lg*8]), Al=ld8(&Hl[l15][k0+lg*8]);
      size_t boff=(size_t)(w*16+l15)*128 + k0 + lg*8;
      bf16x8 Bh=ld8(w2T_h+boff), Bl=ld8(w2T_l+boff);
      z = MFMA(Ah,Bl,z); z = MFMA(Al,Bh,z); z = MFMA(Ah,Bh,z);
    }
    int col = w*16+l15;
    float mb = msg_b2[col];
    #pragma unroll
    for (int r=0;r<4;r++){
      int row = lg*4+r;
      float v = z[r]+mb;
      upd_out[(size_t)(a0+row)*128 + col] = v;
      split_store(v, &Uh[row][col], &Ul[row][col]);
    }
  }
  __syncthreads();

  // qkv: upd @ attn_w_in^T + b ; emit bf16 Q(scaled)/K/V^T
  #pragma unroll
  for (int t3=0; t3<3; t3++){
    f32x4 z = {0.f,0.f,0.f,0.f};
    int col = (w*3+t3)*16 + l15;
    #pragma unroll
    for (int ch=0; ch<4; ch++){
      int k0=ch*32;
      bf16x8 Ah=ld8(&Uh[l15][k0+lg*8]), Al=ld8(&Ul[l15][k0+lg*8]);
      size_t boff=(size_t)col*128 + k0 + lg*8;
      bf16x8 Bh=ld8(awin_h+boff), Bl=ld8(awin_l+boff);
      z = MFMA(Ah,Bl,z); z = MFMA(Al,Bh,z); z = MFMA(Ah,Bh,z);
    }
    float ab = attn_b_in[col];
    int p = col>>7, hh = (col>>5)&3, dd = col&31;
    #pragma unroll
    for (int r=0;r<4;r++){
      int row = a0 + lg*4 + r;
      float v = z[r]+ab;
      if (p==0)      Qbf[(size_t)hh*131072 + (size_t)row*32 + dd] =
                       (unsigned short)f2bf(v*0.17677669529663687f);
      else if (p==1) Kbf[(size_t)hh*131072 + (size_t)row*32 + dd] = (unsigned short)f2bf(v);
      else           Vtb[(size_t)hh*131072 + (size_t)dd*4096 + row] = (unsigned short)f2bf(v);
    }
  }
}

// ---------- barrier-free MFMA flash attention ----------
// 512 blocks x 8 waves; wave = (qjob local 0..1, key-slice 0..3); 16 q/wave.
// Swapped QK^T (S^T): lane l15 = query, 16 scores/lane -> 2-shfl reductions.
__global__ __launch_bounds__(512) void attn_kernel(
  const unsigned short* __restrict__ Qbf, const unsigned short* __restrict__ Kbf,
  const unsigned short* __restrict__ Vtb, float* __restrict__ att)
{
  const int tid = threadIdx.x;
  const int w = tid>>6, lane = tid&63, l15 = lane&15, lg = lane>>4;
  const int qjl = w>>2, ks = w&3;
  const int qj = blockIdx.x*2 + qjl;
  const int h = qj >> 8, qt = qj & 255;

  __shared__ unsigned short Ps[8][16][72];   // per-wave P rows [query][key]
  __shared__ float MBo[2][4][16][32];
  __shared__ float MBm[2][4][16];
  __shared__ float MBs[2][4][16];

  const unsigned short* Kb = Kbf + (size_t)h*131072;
  const unsigned short* Vb = Vtb + (size_t)h*131072;

  bf16x8 bQ = ld8(&Qbf[(size_t)h*131072 + (size_t)(qt*16+l15)*32 + lg*8]);

  float m = -3e38f, su = 0.f;
  f32x4 oacc[2] = {{0.f,0.f,0.f,0.f},{0.f,0.f,0.f,0.f}};

  for (int kt = ks*16; kt < ks*16 + 16; ++kt){
    const int k0 = kt*64;
    f32x4 s[4];
    #pragma unroll
    for (int n=0;n<4;n++){
      bf16x8 aK = ld8(&Kb[(size_t)(k0+n*16+l15)*32 + lg*8]);
      f32x4 z = {0.f,0.f,0.f,0.f};
      s[n] = MFMA(aK, bQ, z);   // C[key=lg*4+r][query=l15]
    }
    float tmax = s[0][0];
    #pragma unroll
    for (int n=0;n<4;n++)
      #pragma unroll
      for (int r=0;r<4;r++) tmax = fmaxf(tmax, s[n][r]);
    tmax = fmaxf(tmax, __shfl_xor(tmax,16,64));
    tmax = fmaxf(tmax, __shfl_xor(tmax,32,64));
    float mn = fmaxf(m, tmax);
    float csc = __expf(m - mn);
    m = mn;
    float psum = 0.f;
    unsigned int* prow = (unsigned int*)&Ps[w][l15][0];
    #pragma unroll
    for (int n=0;n<4;n++){
      float p0=__expf(s[n][0]-mn), p1=__expf(s[n][1]-mn);
      float p2=__expf(s[n][2]-mn), p3=__expf(s[n][3]-mn);
      psum += (p0+p1)+(p2+p3);
      prow[n*8+lg*2]   = f2bf(p0) | (f2bf(p1)<<16);
      prow[n*8+lg*2+1] = f2bf(p2) | (f2bf(p3)<<16);
    }
    psum += __shfl_xor(psum,16,64);
    psum += __shfl_xor(psum,32,64);
    su = su*csc + psum;
    float cr[4];
    #pragma unroll
    for (int r=0;r<4;r++) cr[r] = __shfl(csc, lg*4+r, 64);
    #pragma unroll
    for (int nd=0;nd<2;nd++)
      #pragma unroll
      for (int r=0;r<4;r++) oacc[nd][r] *= cr[r];
    __asm__ volatile("s_waitcnt lgkmcnt(0)" ::: "memory");
    #pragma unroll
    for (int kc=0;kc<2;kc++){
      bf16x8 aP = ld8(&Ps[w][l15][kc*32 + lg*8]);
      #pragma unroll
      for (int nd=0;nd<2;nd++){
        bf16x8 bV = ld8(&Vb[(size_t)(nd*16+l15)*4096 + k0 + kc*32 + lg*8]);
        oacc[nd] = MFMA(aP, bV, oacc[nd]);   // C[q=lg*4+r][d=l15]
      }
    }
  }

  if (lg==0){ MBm[qjl][ks][l15]=m; MBs[qjl][ks][l15]=su; }
  #pragma unroll
  for (int nd=0;nd<2;nd++)
    #pragma unroll
    for (int r=0;r<4;r++) MBo[qjl][ks][lg*4+r][nd*16+l15] = oacc[nd][r];
  __syncthreads();

  for (int idx = tid; idx < 1024; idx += 512){
    int qq = idx>>9, q = (idx>>5)&15, d = idx&31;
    float m0=MBm[qq][0][q], m1=MBm[qq][1][q], m2=MBm[qq][2][q], m3=MBm[qq][3][q];
    float mf = fmaxf(fmaxf(m0,m1), fmaxf(m2,m3));
    float c0=__expf(m0-mf), c1=__expf(m1-mf), c2=__expf(m2-mf), c3=__expf(m3-mf);
    float st = MBs[qq][0][q]*c0 + MBs[qq][1][q]*c1 + MBs[qq][2][q]*c2 + MBs[qq][3][q]*c3;
    float o  = MBo[qq][0][q][d]*c0 + MBo[qq][1][q][d]*c1 + MBo[qq][2][q][d]*c2 + MBo[qq][3][q][d]*c3;
    int qj2 = blockIdx.x*2 + qq;
    int hh = qj2>>8, qrow = (qj2&255)*16 + q;
    att[(size_t)qrow*128 + hh*32 + d] = o/st;
  }
}

// ---------- epilogue: 8 atoms, 512 threads, LDS-staged operands ----------
__global__ __launch_bounds__(512) void final_kernel(
  const float* __restrict__ att, const float* __restrict__ upd,
  const float* __restrict__ wt_out, const float* __restrict__ attn_b_out,
  const float* __restrict__ gate_w, const float* __restrict__ gate_b,
  const float* __restrict__ out_w, const float* __restrict__ out_b,
  float* __restrict__ out)
{
  const int a0 = blockIdx.x*8, tid = threadIdx.x;
  const int g = tid >> 7, o = tid & 127;
  __shared__ float att_s[8][128], upd_s[8][128], tmps[8][128];
  for (int i=tid; i<1024; i+=512){
    int a8 = i>>7, k = i&127;
    att_s[a8][k] = att[(a0+a8)*128+k];
    upd_s[a8][k] = upd[(a0+a8)*128+k];
  }
  __syncthreads();
  const int aA = 2*g, aB = 2*g+1;
  float a2A = attn_b_out[o], a2B = a2A;
  float gA = gate_b[o], gB = gA;
  for (int k=0;k<128;k++){
    float wa = wt_out[k*128+o];
    float wg = gate_w[k*128+o];
    a2A += att_s[aA][k]*wa; a2B += att_s[aB][k]*wa;
    gA  += upd_s[aA][k]*wg; gB  += upd_s[aB][k]*wg;
  }
  gA = sigmoid_f(gA); gB = sigmoid_f(gB);
  tmps[aA][o] = gA*a2A + (1.f-gA)*upd_s[aA][o];
  tmps[aB][o] = gB*a2B + (1.f-gB)*upd_s[aB][o];
  __syncthreads();
  float ouA = out_b[o], ouB = ouA;
  for (int k=0;k<128;k++){
    float w = out_w[k*128+o];
    ouA += tmps[aA][k]*w; ouB += tmps[aB][k]*w;
  }
  out[(a0+aA)*128+o] = ouA;
  out[(a0+aB)*128+o] = ouB;
}

extern "C" void kernel_launch(void* const* d_in, const int* in_sizes, int n_in,
                              void* d_out, int out_size, void* d_ws, size_t ws_size,
                              hipStream_t stream){
  const int*   atomic_numbers = (const int*)  d_in[0];
  const int*   edge_index     = (const int*)  d_in[2];
  const float* edge_vectors   = (const float*)d_in[3];
  const float* edge_lengths   = (const float*)d_in[4];
  const float* atom_embed     = (const float*)d_in[5];
  const float* rad_w1 = (const float*)d_in[6];
  const float* rad_b1 = (const float*)d_in[7];
  const float* rad_w2 = (const float*)d_in[8];
  const float* rad_b2 = (const float*)d_in[9];
  const float* tp_w   = (const float*)d_in[10];
  const float* tp_b   = (const float*)d_in[11];
  const float* msg_w1 = (const float*)d_in[12];
  const float* msg_b1 = (const float*)d_in[13];
  const float* msg_w2 = (const float*)d_in[14];
  const float* msg_b2 = (const float*)d_in[15];
  const float* attn_w_in  = (const float*)d_in[16];
  const float* attn_b_in  = (const float*)d_in[17];
  const float* attn_w_out = (const float*)d_in[18];
  const float* attn_b_out = (const float*)d_in[19];
  const float* gate_w = (const float*)d_in[20];
  const float* gate_b = (const float*)d_in[21];
  const float* out_w  = (const float*)d_in[22];
  const float* out_b  = (const float*)d_in[23];

  // workspace layout (bytes)
  char* ws = (char*)d_ws;
  int* counts    = (int*)(ws);                       // [0,16384)
  int* cursor    = (int*)(ws + 16384);               // [16384,32768)
  int* offsets   = (int*)(ws + 32768);               // [32768,49156)
  int* edge_list = (int*)(ws + 53248);               // [53248,577536)
  float* wt_out  = (float*)(ws + 577536);            // [577536,643072)
  unsigned short* w2t_h  = (unsigned short*)(ws + 643072);   // 16 KB
  unsigned short* w2t_l  = (unsigned short*)(ws + 659456);   // 16 KB
  unsigned short* tpwT_h = (unsigned short*)(ws + 675840);   // 288 KB
  unsigned short* tpwT_l = (unsigned short*)(ws + 970752);   // 288 KB
  unsigned short* w1T_h  = (unsigned short*)(ws + 1265664);  // 48 KB
  unsigned short* w1T_l  = (unsigned short*)(ws + 1314816);  // 48 KB
  unsigned short* w2T_h  = (unsigned short*)(ws + 1363968);  // 32 KB
  unsigned short* w2T_l  = (unsigned short*)(ws + 1396736);  // 32 KB
  unsigned short* awin_h = (unsigned short*)(ws + 1429504);  // 96 KB
  unsigned short* awin_l = (unsigned short*)(ws + 1527808);  // 96 KB
  unsigned short* Fbf_h  = (unsigned short*)(ws + 1626112);  // 9.44 MB
  unsigned short* Fbf_l  = (unsigned short*)(ws + 11063296); // 9.44 MB
  float* att     = (float*)(ws + 1626112);           // aliases Fbf_h (dead after node)
  float* upd     = (float*)(ws + 20500480);          // 2 MB
  unsigned short* Qbf = (unsigned short*)(ws + 22597632);    // 1 MB
  unsigned short* Kbf = (unsigned short*)(ws + 23646208);    // 1 MB
  unsigned short* Vtb = (unsigned short*)(ws + 24694784);    // 1 MB (end 25743360)

  prep_kernel<<<1024, 256, 0, stream>>>(attn_w_out, rad_w2, tp_w, msg_w1, msg_w2, attn_w_in,
      wt_out, w2t_h, w2t_l, tpwT_h, tpwT_l, w1T_h, w1T_l, w2T_h, w2T_l, awin_h, awin_l);
  hipMemsetAsync(ws, 0, 32768, stream);  // counts + cursor
  hist_kernel<<<(N_EDGES+255)/256, 256, 0, stream>>>(edge_index, counts);
  scan_kernel<<<1, 1024, 0, stream>>>(counts, offsets);
  scatter_kernel<<<(N_EDGES+255)/256, 256, 0, stream>>>(edge_index, offsets, cursor, edge_list);
  edge_F_kernel<<<N_ATOMS, 512, 0, stream>>>(edge_vectors, edge_lengths,
      rad_w1, rad_b1, w2t_h, w2t_l, rad_b2, offsets, edge_list, Fbf_h, Fbf_l);
  node_kernel<<<N_ATOMS/16, 512, 0, stream>>>(atomic_numbers, atom_embed,
      Fbf_h, Fbf_l, tpwT_h, tpwT_l, tp_b, offsets,
      w1T_h, w1T_l, msg_b1, w2T_h, w2T_l, msg_b2, awin_h, awin_l, attn_b_in,
      upd, Qbf, Kbf, Vtb);
  attn_kernel<<<512, 512, 0, stream>>>(Qbf, Kbf, Vtb, att);
  final_kernel<<<N_ATOMS/8, 512, 0, stream>>>(att, upd, wt_out, attn_b_out,
      gate_w, gate_b, out_w, out_b, (float*)d_out);
}

// Round 14
// 209.684 us; speedup vs baseline: 2.1285x; 1.0266x over previous
//
#include <hip/hip_runtime.h>
#include <math.h>

#define N_ATOMS 4096
#define N_EDGES 131072
#define PI6 0.52359877559829887f

typedef __attribute__((ext_vector_type(8))) short bf16x8;
typedef __attribute__((ext_vector_type(4))) float f32x4;

#define MFMA(A,B,C) __builtin_amdgcn_mfma_f32_16x16x32_bf16((A),(B),(C),0,0,0)

__device__ __forceinline__ float silu_f(float x){ return x / (1.f + __expf(-x)); }
__device__ __forceinline__ float sigmoid_f(float x){ return 1.f / (1.f + __expf(-x)); }
__device__ __forceinline__ unsigned int f2bf(float f){
  unsigned int u = __float_as_uint(f);
  return (u + 0x7FFFu + ((u>>16)&1u)) >> 16;
}
__device__ __forceinline__ bf16x8 ld8(const unsigned short* p){
  union { unsigned int u[4]; bf16x8 v; } r;
  const unsigned int* q = (const unsigned int*)p;
  r.u[0]=q[0]; r.u[1]=q[1]; r.u[2]=q[2]; r.u[3]=q[3];
  return r.v;
}
__device__ __forceinline__ void split_store(float v, unsigned short* ph, unsigned short* pl){
  unsigned int hb = f2bf(v);
  *ph = (unsigned short)hb;
  *pl = (unsigned short)f2bf(v - __uint_as_float(hb<<16));
}

// ---------- prep: wt_out transpose (fp32) + all bf16 hi/lo weight planes ----------
__global__ __launch_bounds__(256) void prep_kernel(
  const float* __restrict__ attn_w_out, const float* __restrict__ rad_w2,
  const float* __restrict__ tp_w, const float* __restrict__ msg_w1,
  const float* __restrict__ msg_w2, const float* __restrict__ attn_w_in,
  float* __restrict__ wt_out,
  unsigned short* __restrict__ w2t_h, unsigned short* __restrict__ w2t_l,
  unsigned short* __restrict__ tpwT_h, unsigned short* __restrict__ tpwT_l,
  unsigned short* __restrict__ w1T_h, unsigned short* __restrict__ w1T_l,
  unsigned short* __restrict__ w2T_h, unsigned short* __restrict__ w2T_l,
  unsigned short* __restrict__ awin_h, unsigned short* __restrict__ awin_l)
{
  int idx = blockIdx.x*256 + threadIdx.x;
  if (idx < 16384){                       // wt_out: [128][128] transpose fp32
    int i = idx>>7, k = idx&127;
    wt_out[k*128+i] = attn_w_out[idx];
  } else if (idx < 24576){                // w2t: rad_w2^T hi/lo [128][64]
    int j = idx - 16384; int k = j>>7, c = j&127;
    split_store(rad_w2[k*128+c], &w2t_h[c*64+k], &w2t_l[c*64+k]);
  } else if (idx < 172032){               // tpwT: [128 col][1152 k] reordered
    int j = idx - 24576; int col = j&127, kk = j>>7;
    int jj = kk>>7, c = kk&127;
    int r = (jj==0)? c : (jj<4 ? 128 + c*3 + (jj-1) : 512 + c*5 + (jj-4));
    split_store(tp_w[r*128+col], &tpwT_h[col*1152+kk], &tpwT_l[col*1152+kk]);
  } else if (idx < 196608){               // w1T: [128][192]
    int j = idx - 172032; int col = j&127, k = j>>7;
    split_store(msg_w1[k*128+col], &w1T_h[col*192+k], &w1T_l[col*192+k]);
  } else if (idx < 212992){               // w2T: [128][128]
    int j = idx - 196608; int col = j&127, k = j>>7;
    split_store(msg_w2[k*128+col], &w2T_h[col*128+k], &w2T_l[col*128+k]);
  } else if (idx < 262144){               // awin: attn_w_in [384][128] as-is
    int j = idx - 212992;
    split_store(attn_w_in[j], &awin_h[j], &awin_l[j]);
  }
}

// ---------- counting sort of edges by destination ----------
__global__ void hist_kernel(const int* __restrict__ edge_index, int* __restrict__ counts){
  int e = blockIdx.x*blockDim.x + threadIdx.x;
  if (e < N_EDGES) atomicAdd(&counts[edge_index[N_EDGES + e]], 1);
}

__global__ void scan_kernel(const int* __restrict__ counts, int* __restrict__ offsets){
  __shared__ int buf[4096];
  int t = threadIdx.x; // 1024 threads
  for (int i=t;i<4096;i+=1024) buf[i]=counts[i];
  __syncthreads();
  for (int off=1; off<4096; off<<=1){
    int v[4];
    #pragma unroll
    for (int k=0;k<4;k++){ int i=t+k*1024; v[k] = (i>=off)?buf[i-off]:0; }
    __syncthreads();
    #pragma unroll
    for (int k=0;k<4;k++){ int i=t+k*1024; buf[i]+=v[k]; }
    __syncthreads();
  }
  for (int i=t;i<4096;i+=1024) offsets[i]=buf[i]-counts[i]; // exclusive
  if (t==0) offsets[4096]=buf[4095];
}

__global__ void scatter_kernel(const int* __restrict__ edge_index, const int* __restrict__ offsets,
                               int* __restrict__ cursor, int* __restrict__ edge_list){
  int e = blockIdx.x*blockDim.x + threadIdx.x;
  if (e < N_EDGES){
    int d = edge_index[N_EDGES + e];
    int pos = atomicAdd(&cursor[d], 1);
    edge_list[offsets[d] + pos] = e;
  }
}

// ---------- per-atom edge features: all-MFMA pipeline, 4 atoms/block ----------
// W2/W1 staged ONCE per block (was once per atom: 40% of kernel at deg=32).
__global__ __launch_bounds__(512) void edge_F_kernel(
  const float* __restrict__ edge_vectors, const float* __restrict__ edge_lengths,
  const float* __restrict__ rad_w1, const float* __restrict__ rad_b1,
  const unsigned short* __restrict__ w2t_h, const unsigned short* __restrict__ w2t_l,
  const float* __restrict__ rad_b2,
  const int* __restrict__ offsets, const int* __restrict__ edge_list,
  unsigned short* __restrict__ Fh, unsigned short* __restrict__ Fl)
{
  const int tid = threadIdx.x;
  const int w = tid >> 6, lane = tid & 63;
  const int l15 = lane & 15, lg = lane >> 4;
  const int wm = w >> 2, wn2 = w & 3;

  __shared__ unsigned short W2h[128][72], W2l[128][72];
  __shared__ unsigned short W1h[64][36],  W1l[64][36];
  __shared__ unsigned short RBh[32][36],  RBl[32][36];
  __shared__ unsigned short SHh[16][36],  SHl[16][36];
  __shared__ unsigned short R1h[32][72],  R1l[32][72];
  __shared__ unsigned short R2h[128][36], R2l[128][36];

  {
    const unsigned int* gh = (const unsigned int*)w2t_h;
    const unsigned int* gl = (const unsigned int*)w2t_l;
    for (int i = tid; i < 4096; i += 512){
      int c = i >> 5, kp = i & 31;
      *(unsigned int*)&W2h[c][kp*2] = gh[i];
      *(unsigned int*)&W2l[c][kp*2] = gl[i];
    }
  }
  for (int i = tid; i < 2048; i += 512){
    int c = i >> 5, k = i & 31;
    float v = (k < 8) ? rad_w1[k*64 + c] : 0.f;
    split_store(v, &W1h[c][k], &W1l[c][k]);
  }
  for (int i = tid; i < 32*36; i += 512){ RBh[i/36][i%36]=0; RBl[i/36][i%36]=0; }
  for (int i = tid; i < 16*36; i += 512){ SHh[i/36][i%36]=0; SHl[i/36][i%36]=0; }

  const float b1v  = rad_b1[wn2*16 + l15];
  const float b2c0 = rad_b2[wn2*32 + l15];
  const float b2c1 = rad_b2[wn2*32 + 16 + l15];

  __syncthreads();

  for (int aa = 0; aa < 4; ++aa){
    const int a = blockIdx.x*4 + aa;
    const int beg = offsets[a], end = offsets[a+1];
    f32x4 facc = {0.f,0.f,0.f,0.f};

    for (int t0 = beg; t0 < end; t0 += 32){
      // phase A: rbf (threads 0..255) + sh^T (threads 256..511)
      if (tid < 256){
        int e8 = tid >> 3, k = tid & 7;
        int ei = t0 + e8;
        int eid = edge_list[ei < end ? ei : beg];
        float d = edge_lengths[eid];
        float cut = 0.5f*(__cosf(d*PI6)+1.f)*(d<6.f?1.f:0.f);
        float rb = __sinf(d*((float)(k+1)*PI6))/d*cut;
        split_store(rb, &RBh[e8][k], &RBl[e8][k]);
      } else {
        int e8 = (tid-256) >> 3, u = tid & 7;
        int ei = t0 + e8;
        bool val = ei < end;
        int eid = edge_list[val ? ei : beg];
        float vx = edge_vectors[eid*3], vy = edge_vectors[eid*3+1], vz = edge_vectors[eid*3+2];
        float rn = sqrtf(vx*vx+vy*vy+vz*vz) + 1e-8f;
        float x = vx/rn, y = vy/rn, z = vz/rn;
        float sv;
        switch(u){
          case 0: sv = 1.f; break;
          case 1: sv = y; break;
          case 2: sv = z; break;
          case 3: sv = x; break;
          case 4: sv = 3.f*z*z-1.f; break;
          case 5: sv = x*z; break;
          case 6: sv = y*z; break;
          default: sv = x*y; break;
        }
        if (!val) sv = 0.f;
        split_store(sv, &SHh[u][e8], &SHl[u][e8]);
        if (u == 0){
          float s8 = val ? (x*x - y*y) : 0.f;
          split_store(s8, &SHh[8][e8], &SHl[8][e8]);
        }
      }
      __syncthreads();

      // phase B: r1 = silu(rbf @ W1 + b1)
      {
        bf16x8 Ah = ld8(&RBh[wm*16 + l15][lg*8]);
        bf16x8 Al = ld8(&RBl[wm*16 + l15][lg*8]);
        bf16x8 Bh = ld8(&W1h[wn2*16 + l15][lg*8]);
        bf16x8 Bl = ld8(&W1l[wn2*16 + l15][lg*8]);
        f32x4 z = {0.f,0.f,0.f,0.f};
        z = MFMA(Ah,Bl,z); z = MFMA(Al,Bh,z); z = MFMA(Ah,Bh,z);
        #pragma unroll
        for (int r=0;r<4;r++){
          int e8 = wm*16 + lg*4 + r;
          int c  = wn2*16 + l15;
          float v = silu_f(z[r] + b1v);
          split_store(v, &R1h[e8][c], &R1l[e8][c]);
        }
      }
      __syncthreads();

      // phase C: r2 = silu(r1 @ W2 + b2), stored transposed (c-major)
      {
        bf16x8 Ah0 = ld8(&R1h[wm*16+l15][lg*8]);
        bf16x8 Ah1 = ld8(&R1h[wm*16+l15][32+lg*8]);
        bf16x8 Al0 = ld8(&R1l[wm*16+l15][lg*8]);
        bf16x8 Al1 = ld8(&R1l[wm*16+l15][32+lg*8]);
        #pragma unroll
        for (int nt=0; nt<2; nt++){
          int c16 = wn2*2 + nt;
          bf16x8 Bh0 = ld8(&W2h[c16*16+l15][lg*8]);
          bf16x8 Bh1 = ld8(&W2h[c16*16+l15][32+lg*8]);
          bf16x8 Bl0 = ld8(&W2l[c16*16+l15][lg*8]);
          bf16x8 Bl1 = ld8(&W2l[c16*16+l15][32+lg*8]);
          f32x4 z = {0.f,0.f,0.f,0.f};
          z = MFMA(Al0,Bh0,z); z = MFMA(Al1,Bh1,z);
          z = MFMA(Ah0,Bl0,z); z = MFMA(Ah1,Bl1,z);
          z = MFMA(Ah0,Bh0,z); z = MFMA(Ah1,Bh1,z);
          float bb = nt ? b2c1 : b2c0;
          #pragma unroll
          for (int r=0;r<4;r++){
            int e8 = wm*16 + lg*4 + r;
            int c  = c16*16 + l15;
            float v = silu_f(z[r] + bb);
            split_store(v, &R2h[c][e8], &R2l[c][e8]);
          }
        }
      }
      __syncthreads();

      // phase D: F += r2^T @ sh^T ; C-reg accumulate
      {
        bf16x8 Ah = ld8(&R2h[w*16+l15][lg*8]);
        bf16x8 Al = ld8(&R2l[w*16+l15][lg*8]);
        bf16x8 Bh = ld8(&SHh[l15][lg*8]);
        bf16x8 Bl = ld8(&SHl[l15][lg*8]);
        facc = MFMA(Ah,Bl,facc);
        facc = MFMA(Al,Bh,facc);
        facc = MFMA(Ah,Bh,facc);
      }
      __syncthreads();
    }

    // write F planes for atom a: wave w owns c = w*16 + lg*4 + r ; col l15 = j
    if (l15 < 9){
      #pragma unroll
      for (int r=0;r<4;r++){
        int c = w*16 + lg*4 + r;
        size_t o = (size_t)l15*(N_ATOMS*128) + (size_t)a*128 + c;
        split_store(facc[r], &Fh[o], &Fl[o]);
      }
    }
  }
}

// ---------- fused node: agg GEMM + msg MLP + qkv (bf16 Q/K/V^T out) ----------
__global__ __launch_bounds__(512) void node_kernel(
  const int* __restrict__ atomic_numbers, const float* __restrict__ atom_embed,
  const unsigned short* __restrict__ Fh, const unsigned short* __restrict__ Fl,
  const unsigned short* __restrict__ tpwT_h, const unsigned short* __restrict__ tpwT_l,
  const float* __restrict__ tp_b, const int* __restrict__ offsets,
  const unsigned short* __restrict__ w1T_h, const unsigned short* __restrict__ w1T_l,
  const float* __restrict__ msg_b1,
  const unsigned short* __restrict__ w2T_h, const unsigned short* __restrict__ w2T_l,
  const float* __restrict__ msg_b2,
  const unsigned short* __restrict__ awin_h, const unsigned short* __restrict__ awin_l,
  const float* __restrict__ attn_b_in,
  float* __restrict__ upd_out,
  unsigned short* __restrict__ Qbf, unsigned short* __restrict__ Kbf,
  unsigned short* __restrict__ Vtb)
{
  const int a0 = blockIdx.x*16, tid = threadIdx.x;
  const int w = tid>>6, lane = tid&63, l15 = lane&15, lg = lane>>4;

  __shared__ unsigned short Ch[16][200], Cl[16][200];
  __shared__ unsigned short Hh[16][136], Hl[16][136];
  __shared__ unsigned short Uh[16][136], Ul[16][136];

  for (int i=tid; i<1024; i+=512){
    int a16=i>>6, k=i&63;
    float v = atom_embed[atomic_numbers[a0+a16]*64+k];
    split_store(v, &Ch[a16][k], &Cl[a16][k]);
  }

  // agg GEMM
  {
    f32x4 z = {0.f,0.f,0.f,0.f};
    for (int ch=0; ch<36; ch++){
      int k0=ch*32, j=k0>>7, c0=k0&127;
      size_t aoff = (size_t)j*(N_ATOMS*128) + (size_t)(a0+l15)*128 + c0 + lg*8;
      bf16x8 Ah=ld8(Fh+aoff), Al=ld8(Fl+aoff);
      size_t boff = (size_t)(w*16+l15)*1152 + k0 + lg*8;
      bf16x8 Bh=ld8(tpwT_h+boff), Bl=ld8(tpwT_l+boff);
      z = MFMA(Ah,Bl,z); z = MFMA(Al,Bh,z); z = MFMA(Ah,Bh,z);
    }
    int col = w*16+l15;
    float tb = tp_b[col];
    #pragma unroll
    for (int r=0;r<4;r++){
      int row = lg*4+r, arow = a0+row;
      float deg = (float)(offsets[arow+1]-offsets[arow]);
      float v = z[r] + tb*deg;
      split_store(v, &Ch[row][64+col], &Cl[row][64+col]);
    }
  }
  __syncthreads();

  // msg1
  {
    f32x4 z = {0.f,0.f,0.f,0.f};
    #pragma unroll
    for (int ch=0; ch<6; ch++){
      int k0=ch*32;
      bf16x8 Ah=ld8(&Ch[l15][k0+lg*8]), Al=ld8(&Cl[l15][k0+lg*8]);
      size_t boff=(size_t)(w*16+l15)*192 + k0 + lg*8;
      bf16x8 Bh=ld8(w1T_h+boff), Bl=ld8(w1T_l+boff);
      z = MFMA(Ah,Bl,z); z = MFMA(Al,Bh,z); z = MFMA(Ah,Bh,z);
    }
    int col = w*16+l15;
    float mb = msg_b1[col];
    #pragma unroll
    for (int r=0;r<4;r++){
      int row = lg*4+r;
      float v = silu_f(z[r]+mb);
      split_store(v, &Hh[row][col], &Hl[row][col]);
    }
  }
  __syncthreads();

  // msg2
  {
    f32x4 z = {0.f,0.f,0.f,0.f};
    #pragma unroll
    for (int ch=0; ch<4; ch++){
      int k0=ch*32;
      bf16x8 Ah=ld8(&Hh[l15][k0+lg*8]), Al=ld8(&Hl[l15][k0+lg*8]);
      size_t boff=(size_t)(w*16+l15)*128 + k0 + lg*8;
      bf16x8 Bh=ld8(w2T_h+boff), Bl=ld8(w2T_l+boff);
      z = MFMA(Ah,Bl,z); z = MFMA(Al,Bh,z); z = MFMA(Ah,Bh,z);
    }
    int col = w*16+l15;
    float mb = msg_b2[col];
    #pragma unroll
    for (int r=0;r<4;r++){
      int row = lg*4+r;
      float v = z[r]+mb;
      upd_out[(size_t)(a0+row)*128 + col] = v;
      split_store(v, &Uh[row][col], &Ul[row][col]);
    }
  }
  __syncthreads();

  // qkv: upd @ attn_w_in^T + b ; emit bf16 Q(scaled)/K/V^T
  #pragma unroll
  for (int t3=0; t3<3; t3++){
    f32x4 z = {0.f,0.f,0.f,0.f};
    int col = (w*3+t3)*16 + l15;
    #pragma unroll
    for (int ch=0; ch<4; ch++){
      int k0=ch*32;
      bf16x8 Ah=ld8(&Uh[l15][k0+lg*8]), Al=ld8(&Ul[l15][k0+lg*8]);
      size_t boff=(size_t)col*128 + k0 + lg*8;
      bf16x8 Bh=ld8(awin_h+boff), Bl=ld8(awin_l+boff);
      z = MFMA(Ah,Bl,z); z = MFMA(Al,Bh,z); z = MFMA(Ah,Bh,z);
    }
    float ab = attn_b_in[col];
    int p = col>>7, hh = (col>>5)&3, dd = col&31;
    #pragma unroll
    for (int r=0;r<4;r++){
      int row = a0 + lg*4 + r;
      float v = z[r]+ab;
      if (p==0)      Qbf[(size_t)hh*131072 + (size_t)row*32 + dd] =
                       (unsigned short)f2bf(v*0.17677669529663687f);
      else if (p==1) Kbf[(size_t)hh*131072 + (size_t)row*32 + dd] = (unsigned short)f2bf(v);
      else           Vtb[(size_t)hh*131072 + (size_t)dd*4096 + row] = (unsigned short)f2bf(v);
    }
  }
}

// ---------- barrier-free MFMA flash attention ----------
__global__ __launch_bounds__(512) void attn_kernel(
  const unsigned short* __restrict__ Qbf, const unsigned short* __restrict__ Kbf,
  const unsigned short* __restrict__ Vtb, float* __restrict__ att)
{
  const int tid = threadIdx.x;
  const int w = tid>>6, lane = tid&63, l15 = lane&15, lg = lane>>4;
  const int qjl = w>>2, ks = w&3;
  const int qj = blockIdx.x*2 + qjl;
  const int h = qj >> 8, qt = qj & 255;

  __shared__ unsigned short Ps[8][16][72];
  __shared__ float MBo[2][4][16][32];
  __shared__ float MBm[2][4][16];
  __shared__ float MBs[2][4][16];

  const unsigned short* Kb = Kbf + (size_t)h*131072;
  const unsigned short* Vb = Vtb + (size_t)h*131072;

  bf16x8 bQ = ld8(&Qbf[(size_t)h*131072 + (size_t)(qt*16+l15)*32 + lg*8]);

  float m = -3e38f, su = 0.f;
  f32x4 oacc[2] = {{0.f,0.f,0.f,0.f},{0.f,0.f,0.f,0.f}};

  for (int kt = ks*16; kt < ks*16 + 16; ++kt){
    const int k0 = kt*64;
    f32x4 s[4];
    #pragma unroll
    for (int n=0;n<4;n++){
      bf16x8 aK = ld8(&Kb[(size_t)(k0+n*16+l15)*32 + lg*8]);
      f32x4 z = {0.f,0.f,0.f,0.f};
      s[n] = MFMA(aK, bQ, z);
    }
    float tmax = s[0][0];
    #pragma unroll
    for (int n=0;n<4;n++)
      #pragma unroll
      for (int r=0;r<4;r++) tmax = fmaxf(tmax, s[n][r]);
    tmax = fmaxf(tmax, __shfl_xor(tmax,16,64));
    tmax = fmaxf(tmax, __shfl_xor(tmax,32,64));
    float mn = fmaxf(m, tmax);
    float csc = __expf(m - mn);
    m = mn;
    float psum = 0.f;
    unsigned int* prow = (unsigned int*)&Ps[w][l15][0];
    #pragma unroll
    for (int n=0;n<4;n++){
      float p0=__expf(s[n][0]-mn), p1=__expf(s[n][1]-mn);
      float p2=__expf(s[n][2]-mn), p3=__expf(s[n][3]-mn);
      psum += (p0+p1)+(p2+p3);
      prow[n*8+lg*2]   = f2bf(p0) | (f2bf(p1)<<16);
      prow[n*8+lg*2+1] = f2bf(p2) | (f2bf(p3)<<16);
    }
    psum += __shfl_xor(psum,16,64);
    psum += __shfl_xor(psum,32,64);
    su = su*csc + psum;
    float cr[4];
    #pragma unroll
    for (int r=0;r<4;r++) cr[r] = __shfl(csc, lg*4+r, 64);
    #pragma unroll
    for (int nd=0;nd<2;nd++)
      #pragma unroll
      for (int r=0;r<4;r++) oacc[nd][r] *= cr[r];
    __asm__ volatile("s_waitcnt lgkmcnt(0)" ::: "memory");
    #pragma unroll
    for (int kc=0;kc<2;kc++){
      bf16x8 aP = ld8(&Ps[w][l15][kc*32 + lg*8]);
      #pragma unroll
      for (int nd=0;nd<2;nd++){
        bf16x8 bV = ld8(&Vb[(size_t)(nd*16+l15)*4096 + k0 + kc*32 + lg*8]);
        oacc[nd] = MFMA(aP, bV, oacc[nd]);
      }
    }
  }

  if (lg==0){ MBm[qjl][ks][l15]=m; MBs[qjl][ks][l15]=su; }
  #pragma unroll
  for (int nd=0;nd<2;nd++)
    #pragma unroll
    for (int r=0;r<4;r++) MBo[qjl][ks][lg*4+r][nd*16+l15] = oacc[nd][r];
  __syncthreads();

  for (int idx = tid; idx < 1024; idx += 512){
    int qq = idx>>9, q = (idx>>5)&15, d = idx&31;
    float m0=MBm[qq][0][q], m1=MBm[qq][1][q], m2=MBm[qq][2][q], m3=MBm[qq][3][q];
    float mf = fmaxf(fmaxf(m0,m1), fmaxf(m2,m3));
    float c0=__expf(m0-mf), c1=__expf(m1-mf), c2=__expf(m2-mf), c3=__expf(m3-mf);
    float st = MBs[qq][0][q]*c0 + MBs[qq][1][q]*c1 + MBs[qq][2][q]*c2 + MBs[qq][3][q]*c3;
    float o  = MBo[qq][0][q][d]*c0 + MBo[qq][1][q][d]*c1 + MBo[qq][2][q][d]*c2 + MBo[qq][3][q][d]*c3;
    int qj2 = blockIdx.x*2 + qq;
    int hh = qj2>>8, qrow = (qj2&255)*16 + q;
    att[(size_t)qrow*128 + hh*32 + d] = o/st;
  }
}

// ---------- epilogue: 8 atoms, 512 threads, LDS-staged operands ----------
__global__ __launch_bounds__(512) void final_kernel(
  const float* __restrict__ att, const float* __restrict__ upd,
  const float* __restrict__ wt_out, const float* __restrict__ attn_b_out,
  const float* __restrict__ gate_w, const float* __restrict__ gate_b,
  const float* __restrict__ out_w, const float* __restrict__ out_b,
  float* __restrict__ out)
{
  const int a0 = blockIdx.x*8, tid = threadIdx.x;
  const int g = tid >> 7, o = tid & 127;
  __shared__ float att_s[8][128], upd_s[8][128], tmps[8][128];
  for (int i=tid; i<1024; i+=512){
    int a8 = i>>7, k = i&127;
    att_s[a8][k] = att[(a0+a8)*128+k];
    upd_s[a8][k] = upd[(a0+a8)*128+k];
  }
  __syncthreads();
  const int aA = 2*g, aB = 2*g+1;
  float a2A = attn_b_out[o], a2B = a2A;
  float gA = gate_b[o], gB = gA;
  for (int k=0;k<128;k++){
    float wa = wt_out[k*128+o];
    float wg = gate_w[k*128+o];
    a2A += att_s[aA][k]*wa; a2B += att_s[aB][k]*wa;
    gA  += upd_s[aA][k]*wg; gB  += upd_s[aB][k]*wg;
  }
  gA = sigmoid_f(gA); gB = sigmoid_f(gB);
  tmps[aA][o] = gA*a2A + (1.f-gA)*upd_s[aA][o];
  tmps[aB][o] = gB*a2B + (1.f-gB)*upd_s[aB][o];
  __syncthreads();
  float ouA = out_b[o], ouB = ouA;
  for (int k=0;k<128;k++){
    float w = out_w[k*128+o];
    ouA += tmps[aA][k]*w; ouB += tmps[aB][k]*w;
  }
  out[(a0+aA)*128+o] = ouA;
  out[(a0+aB)*128+o] = ouB;
}

extern "C" void kernel_launch(void* const* d_in, const int* in_sizes, int n_in,
                              void* d_out, int out_size, void* d_ws, size_t ws_size,
                              hipStream_t stream){
  const int*   atomic_numbers = (const int*)  d_in[0];
  const int*   edge_index     = (const int*)  d_in[2];
  const float* edge_vectors   = (const float*)d_in[3];
  const float* edge_lengths   = (const float*)d_in[4];
  const float* atom_embed     = (const float*)d_in[5];
  const float* rad_w1 = (const float*)d_in[6];
  const float* rad_b1 = (const float*)d_in[7];
  const float* rad_w2 = (const float*)d_in[8];
  const float* rad_b2 = (const float*)d_in[9];
  const float* tp_w   = (const float*)d_in[10];
  const float* tp_b   = (const float*)d_in[11];
  const float* msg_w1 = (const float*)d_in[12];
  const float* msg_b1 = (const float*)d_in[13];
  const float* msg_w2 = (const float*)d_in[14];
  const float* msg_b2 = (const float*)d_in[15];
  const float* attn_w_in  = (const float*)d_in[16];
  const float* attn_b_in  = (const float*)d_in[17];
  const float* attn_w_out = (const float*)d_in[18];
  const float* attn_b_out = (const float*)d_in[19];
  const float* gate_w = (const float*)d_in[20];
  const float* gate_b = (const float*)d_in[21];
  const float* out_w  = (const float*)d_in[22];
  const float* out_b  = (const float*)d_in[23];

  // workspace layout (bytes)
  char* ws = (char*)d_ws;
  int* counts    = (int*)(ws);                       // [0,16384)
  int* cursor    = (int*)(ws + 16384);               // [16384,32768)
  int* offsets   = (int*)(ws + 32768);               // [32768,49156)
  int* edge_list = (int*)(ws + 53248);               // [53248,577536)
  float* wt_out  = (float*)(ws + 577536);            // [577536,643072)
  unsigned short* w2t_h  = (unsigned short*)(ws + 643072);   // 16 KB
  unsigned short* w2t_l  = (unsigned short*)(ws + 659456);   // 16 KB
  unsigned short* tpwT_h = (unsigned short*)(ws + 675840);   // 288 KB
  unsigned short* tpwT_l = (unsigned short*)(ws + 970752);   // 288 KB
  unsigned short* w1T_h  = (unsigned short*)(ws + 1265664);  // 48 KB
  unsigned short* w1T_l  = (unsigned short*)(ws + 1314816);  // 48 KB
  unsigned short* w2T_h  = (unsigned short*)(ws + 1363968);  // 32 KB
  unsigned short* w2T_l  = (unsigned short*)(ws + 1396736);  // 32 KB
  unsigned short* awin_h = (unsigned short*)(ws + 1429504);  // 96 KB
  unsigned short* awin_l = (unsigned short*)(ws + 1527808);  // 96 KB
  unsigned short* Fbf_h  = (unsigned short*)(ws + 1626112);  // 9.44 MB
  unsigned short* Fbf_l  = (unsigned short*)(ws + 11063296); // 9.44 MB
  float* att     = (float*)(ws + 1626112);           // aliases Fbf_h (dead after node)
  float* upd     = (float*)(ws + 20500480);          // 2 MB
  unsigned short* Qbf = (unsigned short*)(ws + 22597632);    // 1 MB
  unsigned short* Kbf = (unsigned short*)(ws + 23646208);    // 1 MB
  unsigned short* Vtb = (unsigned short*)(ws + 24694784);    // 1 MB (end 25743360)

  prep_kernel<<<1024, 256, 0, stream>>>(attn_w_out, rad_w2, tp_w, msg_w1, msg_w2, attn_w_in,
      wt_out, w2t_h, w2t_l, tpwT_h, tpwT_l, w1T_h, w1T_l, w2T_h, w2T_l, awin_h, awin_l);
  hipMemsetAsync(ws, 0, 32768, stream);  // counts + cursor
  hist_kernel<<<(N_EDGES+255)/256, 256, 0, stream>>>(edge_index, counts);
  scan_kernel<<<1, 1024, 0, stream>>>(counts, offsets);
  scatter_kernel<<<(N_EDGES+255)/256, 256, 0, stream>>>(edge_index, offsets, cursor, edge_list);
  edge_F_kernel<<<N_ATOMS/4, 512, 0, stream>>>(edge_vectors, edge_lengths,
      rad_w1, rad_b1, w2t_h, w2t_l, rad_b2, offsets, edge_list, Fbf_h, Fbf_l);
  node_kernel<<<N_ATOMS/16, 512, 0, stream>>>(atomic_numbers, atom_embed,
      Fbf_h, Fbf_l, tpwT_h, tpwT_l, tp_b, offsets,
      w1T_h, w1T_l, msg_b1, w2T_h, w2T_l, msg_b2, awin_h, awin_l, attn_b_in,
      upd, Qbf, Kbf, Vtb);
  attn_kernel<<<512, 512, 0, stream>>>(Qbf, Kbf, Vtb, att);
  final_kernel<<<N_ATOMS/8, 512, 0, stream>>>(att, upd, wt_out, attn_b_out,
      gate_w, gate_b, out_w, out_b, (float*)d_out);
}